// Round 1
// baseline (2363.719 us; speedup 1.0000x reference)
//
#include <hip/hip_runtime.h>
#include <hip/hip_bf16.h>

#define BB 512
#define TT 128

typedef unsigned short u16;
typedef short v8s __attribute__((ext_vector_type(8)));
typedef float f32x4 __attribute__((ext_vector_type(4)));

__device__ __forceinline__ u16 f2bf(float x){
  union { float f; unsigned int u; } v; v.f = x;
  unsigned int r = (v.u + 0x7fffu + ((v.u >> 16) & 1u)) >> 16;
  return (u16)r;
}
__device__ __forceinline__ float sigm(float x){
  x = fminf(fmaxf(x, -30.f), 30.f);
  return 1.f / (1.f + __expf(-x));
}
__device__ __forceinline__ float tanh_f(float x){
  x = fminf(fmaxf(x, -15.f), 15.f);
  float e = __expf(-2.f * x);
  return (1.f - e) / (1.f + e);
}

// ---------------- prep: pack weights into MFMA-fragment order, build xs/biases ----
// frag layout convention (used consistently for A and B packs):
//   tile = j>>4 (16 gate rows), kf = k>>5 (K=32 frag), lane = (j&15) + 16*((k&31)>>3),
//   elem = k&7   -> each lane holds 8 k-consecutive bf16 = one 16B chunk.
__global__ __launch_bounds__(256) void k_prep(
    const float* tseq, const float* init_in,
    const float* Wih0, const float* Whh0, const float* bih0, const float* bhh0,
    const float* Wih1, const float* Whh1, const float* bih1, const float* bhh1,
    float* xs, u16* W0p, u16* W1ip, u16* W1hp,
    float* bias0, float* bias1, float* wv0)
{
  int tid = blockIdx.x * blockDim.x + threadIdx.x;
  int stride = gridDim.x * blockDim.x;
  for (int i = tid; i < TT*BB; i += stride){
    int t = i / BB, b = i % BB;
    xs[i] = (t == 0) ? init_in[0] : tseq[b*TT + (t-1)];
  }
  for (int i = tid; i < 2*512*128; i += stride){
    int d = i / (512*128), r = i % (512*128);
    int j = r / 128, k = r % 128;
    int dst = ((((d*32 + (j>>4))*4 + (k>>5))*64) + ((j&15) + 16*((k&31)>>3)))*8 + (k&7);
    W0p[dst]  = f2bf(Whh0[i]);
    W1hp[dst] = f2bf(Whh1[i]);
  }
  for (int i = tid; i < 2*512*256; i += stride){
    int d = i / (512*256), r = i % (512*256);
    int j = r / 256, k = r % 256;
    int dst = ((((d*32 + (j>>4))*8 + (k>>5))*64) + ((j&15) + 16*((k&31)>>3)))*8 + (k&7);
    W1ip[dst] = f2bf(Wih1[i]);
  }
  for (int i = tid; i < 2*512; i += stride){
    bias0[i] = bih0[i] + bhh0[i];
    bias1[i] = bih1[i] + bhh1[i];
    wv0[i]   = Wih0[i];            // Wih0 is (2,512,1) flat
  }
}

// ---------------- encoder: h0 = tanh(LN(relu(LN(x@W1^T+b1))@W2^T+b2)) ------------
__global__ __launch_bounds__(256) void k_enc(
    const float* phys, const float* W1, const float* b1, const float* g1, const float* be1,
    const float* W2, const float* b2, const float* g2, const float* be2, float* h0enc)
{
  __shared__ float eL[8][256];
  int tid = threadIdx.x;
  int rr = tid >> 5, sub = tid & 31;
  int r = blockIdx.x * 8 + rr;
  float x[16];
#pragma unroll
  for (int k = 0; k < 16; ++k) x[k] = phys[r*16 + k];
  float y[8];
#pragma unroll
  for (int jj = 0; jj < 8; ++jj){
    int j = sub*8 + jj;
    float s = b1[j];
#pragma unroll
    for (int k = 0; k < 16; ++k) s += x[k] * W1[j*16 + k];
    y[jj] = s;
  }
  float sum = 0.f, sq = 0.f;
#pragma unroll
  for (int jj = 0; jj < 8; ++jj){ sum += y[jj]; sq += y[jj]*y[jj]; }
#pragma unroll
  for (int m = 16; m >= 1; m >>= 1){ sum += __shfl_xor(sum, m, 32); sq += __shfl_xor(sq, m, 32); }
  float mu = sum / 256.f;
  float rs = rsqrtf(sq / 256.f - mu*mu + 1e-5f);
#pragma unroll
  for (int jj = 0; jj < 8; ++jj){
    int j = sub*8 + jj;
    eL[rr][j] = fmaxf((y[jj] - mu) * rs * g1[j] + be1[j], 0.f);
  }
  __syncthreads();
  float y2[4];
#pragma unroll
  for (int jj = 0; jj < 4; ++jj){
    int j2 = sub*4 + jj;
    float s = b2[j2];
    const float* wrow = W2 + j2*256;
    for (int k = 0; k < 256; k += 4)
      s += eL[rr][k]*wrow[k] + eL[rr][k+1]*wrow[k+1] + eL[rr][k+2]*wrow[k+2] + eL[rr][k+3]*wrow[k+3];
    y2[jj] = s;
  }
  sum = 0.f; sq = 0.f;
#pragma unroll
  for (int jj = 0; jj < 4; ++jj){ sum += y2[jj]; sq += y2[jj]*y2[jj]; }
#pragma unroll
  for (int m = 16; m >= 1; m >>= 1){ sum += __shfl_xor(sum, m, 32); sq += __shfl_xor(sq, m, 32); }
  mu = sum / 128.f;
  rs = rsqrtf(sq / 128.f - mu*mu + 1e-5f);
#pragma unroll
  for (int jj = 0; jj < 4; ++jj){
    int j2 = sub*4 + jj;
    h0enc[r*128 + j2] = tanh_f((y2[jj]-mu)*rs*g2[j2] + be2[j2]);
  }
}

// ---------------- layer0 recurrence: 64 blocks = (dir, 16-row batch tile) --------
__global__ __launch_bounds__(512) void k_l0(
    const u16* W0p, const float* bias0, const float* wv0, const float* xs,
    const float* h0enc, u16* o0pack)
{
  __shared__ __align__(16) u16 Xb[2][4][512];
  int bx = blockIdx.x;
  int tile = bx & 31, d = bx >> 5;
  int tid = threadIdx.x, w = tid >> 6, l = tid & 63;
  int r0 = tile * 16, lrow = l & 15, lk = l >> 4;

  if (tid < 256){                 // init h buffer 0 from encoder output
    int kf = tid >> 6, ll = tid & 63;
    const float* src = h0enc + (r0 + (ll & 15))*128 + kf*32 + 8*(ll >> 4);
    u16* dstp = &Xb[0][kf][ll*8];
#pragma unroll
    for (int i = 0; i < 8; ++i) dstp[i] = f2bf(src[i]);
  }

  float bias[4][4], wv[4][4];
#pragma unroll
  for (int q = 0; q < 4; ++q){
    int tq = w + 8*q;             // q: 0=i 1=f 2=g 3=o, same 16 channels per wave
#pragma unroll
    for (int jj = 0; jj < 4; ++jj){
      int j = tq*16 + 4*lk + jj;
      bias[q][jj] = bias0[d*512 + j];
      wv[q][jj]   = wv0[d*512 + j];
    }
  }
  float c[4] = {0.f,0.f,0.f,0.f};
  const u16* Wb = W0p + (size_t)d*32*4*512;
  int jout = w*16 + 4*lk;
  int kfx = jout >> 5;
  int sl  = lrow + 16*((jout & 31) >> 3);
  int eb  = jout & 7;
  int kfo = 4*d + kfx;
  __syncthreads();

  for (int t = 0; t < TT; ++t){
    int cur = t & 1, nxt = cur ^ 1;
    v8s bfr[4];
#pragma unroll
    for (int kf = 0; kf < 4; ++kf) bfr[kf] = *(const v8s*)&Xb[cur][kf][l*8];
    f32x4 acc[4];
#pragma unroll
    for (int q = 0; q < 4; ++q) acc[q] = (f32x4){0.f,0.f,0.f,0.f};
#pragma unroll
    for (int kf = 0; kf < 4; ++kf){
#pragma unroll
      for (int q = 0; q < 4; ++q){
        int tq = w + 8*q;
        v8s a = *(const v8s*)(Wb + (size_t)((tq*4 + kf)*64 + l)*8);
        acc[q] = __builtin_amdgcn_mfma_f32_16x16x32_bf16(a, bfr[kf], acc[q], 0, 0, 0);
      }
    }
    float xv = xs[t*BB + r0 + lrow];
    float hn[4];
#pragma unroll
    for (int jj = 0; jj < 4; ++jj){
      float gi = acc[0][jj] + bias[0][jj] + xv*wv[0][jj];
      float gf = acc[1][jj] + bias[1][jj] + xv*wv[1][jj];
      float gg = acc[2][jj] + bias[2][jj] + xv*wv[2][jj];
      float go = acc[3][jj] + bias[3][jj] + xv*wv[3][jj];
      float cn = sigm(gf)*c[jj] + sigm(gi)*tanh_f(gg);
      c[jj] = cn;
      hn[jj] = sigm(go)*tanh_f(cn);
    }
    uint2 hp;
    hp.x = (unsigned)f2bf(hn[0]) | ((unsigned)f2bf(hn[1]) << 16);
    hp.y = (unsigned)f2bf(hn[2]) | ((unsigned)f2bf(hn[3]) << 16);
    *(uint2*)&Xb[nxt][kfx][sl*8 + eb] = hp;
    size_t off = ((((size_t)t*32 + tile)*8 + kfo)*64 + sl)*8 + eb;
    *(uint2*)&o0pack[off] = hp;
    __syncthreads();
  }
}

// ---------------- layer1 recurrence ----------------------------------------------
__global__ __launch_bounds__(512) void k_l1(
    const u16* W1ip, const u16* W1hp, const float* bias1,
    const u16* o0pack, const float* h0enc, float* h1store)
{
  __shared__ __align__(16) u16 Xh[2][4][512];
  int bx = blockIdx.x;
  int tile = bx & 31, d = bx >> 5;
  int tid = threadIdx.x, w = tid >> 6, l = tid & 63;
  int r0 = tile * 16, lrow = l & 15, lk = l >> 4;

  if (tid < 256){                 // initial h1 = h0enc too (h_init broadcast)
    int kf = tid >> 6, ll = tid & 63;
    const float* src = h0enc + (r0 + (ll & 15))*128 + kf*32 + 8*(ll >> 4);
    u16* dstp = &Xh[0][kf][ll*8];
#pragma unroll
    for (int i = 0; i < 8; ++i) dstp[i] = f2bf(src[i]);
  }

  float bias[4][4];
#pragma unroll
  for (int q = 0; q < 4; ++q){
    int tq = w + 8*q;
#pragma unroll
    for (int jj = 0; jj < 4; ++jj)
      bias[q][jj] = bias1[d*512 + tq*16 + 4*lk + jj];
  }
  float c[4] = {0.f,0.f,0.f,0.f};
  const u16* Wi = W1ip + (size_t)d*32*8*512;
  const u16* Wh = W1hp + (size_t)d*32*4*512;
  int jout = w*16 + 4*lk;
  int kfx = jout >> 5;
  int sl  = lrow + 16*((jout & 31) >> 3);
  int eb  = jout & 7;
  __syncthreads();

  for (int t = 0; t < TT; ++t){
    int cur = t & 1, nxt = cur ^ 1;
    v8s bh[4];
#pragma unroll
    for (int kf = 0; kf < 4; ++kf) bh[kf] = *(const v8s*)&Xh[cur][kf][l*8];
    v8s bo[8];
#pragma unroll
    for (int kf = 0; kf < 8; ++kf)
      bo[kf] = *(const v8s*)&o0pack[((((size_t)t*32 + tile)*8 + kf)*64 + l)*8];
    f32x4 acc[4];
#pragma unroll
    for (int q = 0; q < 4; ++q) acc[q] = (f32x4){0.f,0.f,0.f,0.f};
#pragma unroll
    for (int kf = 0; kf < 8; ++kf){
#pragma unroll
      for (int q = 0; q < 4; ++q){
        v8s a = *(const v8s*)(Wi + (size_t)(((w + 8*q)*8 + kf)*64 + l)*8);
        acc[q] = __builtin_amdgcn_mfma_f32_16x16x32_bf16(a, bo[kf], acc[q], 0, 0, 0);
      }
    }
#pragma unroll
    for (int kf = 0; kf < 4; ++kf){
#pragma unroll
      for (int q = 0; q < 4; ++q){
        v8s a = *(const v8s*)(Wh + (size_t)(((w + 8*q)*4 + kf)*64 + l)*8);
        acc[q] = __builtin_amdgcn_mfma_f32_16x16x32_bf16(a, bh[kf], acc[q], 0, 0, 0);
      }
    }
    float hn[4];
#pragma unroll
    for (int jj = 0; jj < 4; ++jj){
      float gi = acc[0][jj] + bias[0][jj];
      float gf = acc[1][jj] + bias[1][jj];
      float gg = acc[2][jj] + bias[2][jj];
      float go = acc[3][jj] + bias[3][jj];
      float cn = sigm(gf)*c[jj] + sigm(gi)*tanh_f(gg);
      c[jj] = cn;
      hn[jj] = sigm(go)*tanh_f(cn);
    }
    uint2 hp;
    hp.x = (unsigned)f2bf(hn[0]) | ((unsigned)f2bf(hn[1]) << 16);
    hp.y = (unsigned)f2bf(hn[2]) | ((unsigned)f2bf(hn[3]) << 16);
    *(uint2*)&Xh[nxt][kfx][sl*8 + eb] = hp;
    f32x4 hv = {hn[0], hn[1], hn[2], hn[3]};
    *(f32x4*)&h1store[((size_t)t*BB + r0 + lrow)*256 + d*128 + jout] = hv;
    __syncthreads();
  }
}

// ---------------- head: LN -> proj -> relu head1 -> head2, parallel over (t,b) ---
__global__ __launch_bounds__(256) void k_head(
    const float* h1store, const float* lng, const float* lnb,
    const float* projW, const float* projb,
    const float* hW1, const float* hb1, const float* hW2, const float* hb2,
    float* qout)
{
  __shared__ __align__(16) float xn[16][260];
  __shared__ __align__(16) float pr[16][132];
  int bx = blockIdx.x;
  int t = bx >> 5, rt = bx & 31;
  int tid = threadIdx.x, rr = tid >> 4, g = tid & 15;
  int r = rt*16 + rr;
  const float* src = h1store + ((size_t)t*BB + r)*256;
  float v[16];
#pragma unroll
  for (int i = 0; i < 16; ++i) v[i] = src[g + 16*i];   // coalesced across g
  float sum = 0.f, sq = 0.f;
#pragma unroll
  for (int i = 0; i < 16; ++i){ sum += v[i]; sq += v[i]*v[i]; }
#pragma unroll
  for (int m = 8; m >= 1; m >>= 1){ sum += __shfl_xor(sum, m, 16); sq += __shfl_xor(sq, m, 16); }
  float mu = sum / 256.f;
  float rs = rsqrtf(sq / 256.f - mu*mu + 1e-5f);
#pragma unroll
  for (int i = 0; i < 16; ++i){
    int k = g + 16*i;
    xn[rr][k] = (v[i]-mu)*rs*lng[k] + lnb[k];
  }
  __syncthreads();
  float a8[8];
#pragma unroll
  for (int jj = 0; jj < 8; ++jj) a8[jj] = projb[g*8 + jj];
  const f32x4* xr = (const f32x4*)&xn[rr][0];
  for (int kg = 0; kg < 64; ++kg){
    f32x4 xv = xr[kg];
#pragma unroll
    for (int jj = 0; jj < 8; ++jj){
      f32x4 wq = *(const f32x4*)&projW[(g*8 + jj)*256 + kg*4];
      a8[jj] += xv[0]*wq[0] + xv[1]*wq[1] + xv[2]*wq[2] + xv[3]*wq[3];
    }
  }
#pragma unroll
  for (int jj = 0; jj < 8; ++jj) pr[rr][g*8 + jj] = a8[jj];
  __syncthreads();
  float b8[8];
#pragma unroll
  for (int jj = 0; jj < 8; ++jj) b8[jj] = hb1[g*8 + jj];
  const f32x4* prr = (const f32x4*)&pr[rr][0];
  for (int kg = 0; kg < 32; ++kg){
    f32x4 xv = prr[kg];
#pragma unroll
    for (int jj = 0; jj < 8; ++jj){
      f32x4 wq = *(const f32x4*)&hW1[(g*8 + jj)*128 + kg*4];
      b8[jj] += xv[0]*wq[0] + xv[1]*wq[1] + xv[2]*wq[2] + xv[3]*wq[3];
    }
  }
  float part = 0.f;
#pragma unroll
  for (int jj = 0; jj < 8; ++jj) part += fmaxf(b8[jj], 0.f) * hW2[g*8 + jj];
#pragma unroll
  for (int m = 8; m >= 1; m >>= 1) part += __shfl_xor(part, m, 16);
  if (g == 0) qout[t*BB + r] = part + hb2[0];
}

// ---------------- AR blend: pred_t = t? 0.8 q_t + 0.2 pred_{t-1} : q_0 -----------
__global__ __launch_bounds__(512) void k_blend(const float* qout, float* out)
{
  int b = threadIdx.x;
  float pred = 0.f;
  for (int t0 = 0; t0 < TT; t0 += 16){
    float v[16];
#pragma unroll
    for (int i = 0; i < 16; ++i) v[i] = qout[(t0+i)*BB + b];
#pragma unroll
    for (int i = 0; i < 16; ++i){
      pred = (t0 + i == 0) ? v[i] : 0.8f*v[i] + 0.2f*pred;
      out[b*TT + t0 + i] = pred;
    }
  }
}

extern "C" void kernel_launch(void* const* d_in, const int* in_sizes, int n_in,
                              void* d_out, int out_size, void* d_ws, size_t ws_size,
                              hipStream_t stream) {
  const float* physical   = (const float*)d_in[0];
  const float* target_seq = (const float*)d_in[1];
  const float* enc_W1     = (const float*)d_in[2];
  const float* enc_b1     = (const float*)d_in[3];
  const float* enc_ln1_g  = (const float*)d_in[4];
  const float* enc_ln1_b  = (const float*)d_in[5];
  const float* enc_W2     = (const float*)d_in[6];
  const float* enc_b2     = (const float*)d_in[7];
  const float* enc_ln2_g  = (const float*)d_in[8];
  const float* enc_ln2_b  = (const float*)d_in[9];
  const float* Wih0       = (const float*)d_in[10];
  const float* Whh0       = (const float*)d_in[11];
  const float* bih0       = (const float*)d_in[12];
  const float* bhh0       = (const float*)d_in[13];
  const float* Wih1       = (const float*)d_in[14];
  const float* Whh1       = (const float*)d_in[15];
  const float* bih1       = (const float*)d_in[16];
  const float* bhh1       = (const float*)d_in[17];
  const float* ln_g       = (const float*)d_in[18];
  const float* ln_b       = (const float*)d_in[19];
  const float* proj_W     = (const float*)d_in[20];
  const float* proj_b     = (const float*)d_in[21];
  const float* head_W1    = (const float*)d_in[22];
  const float* head_b1    = (const float*)d_in[23];
  const float* head_W2    = (const float*)d_in[24];
  const float* head_b2    = (const float*)d_in[25];
  const float* init_input = (const float*)d_in[26];

  size_t off = 0;
  char* base = (char*)d_ws;
  auto carve = [&](size_t bytes) -> void* {
    void* p = base + off;
    off += (bytes + 255) & ~(size_t)255;
    return p;
  };
  u16*   o0pack  = (u16*)  carve((size_t)TT*32*8*64*8*2);   // 32 MB bf16, frag-packed
  float* h1store = (float*)carve((size_t)TT*BB*256*4);      // 64 MB f32
  float* qout    = (float*)carve((size_t)TT*BB*4);
  float* h0enc   = (float*)carve((size_t)BB*128*4);
  float* xs      = (float*)carve((size_t)TT*BB*4);
  u16*   W0p     = (u16*)  carve((size_t)2*512*128*2);
  u16*   W1ip    = (u16*)  carve((size_t)2*512*256*2);
  u16*   W1hp    = (u16*)  carve((size_t)2*512*128*2);
  float* bias0   = (float*)carve(4096);
  float* bias1   = (float*)carve(4096);
  float* wv0     = (float*)carve(4096);

  k_prep<<<256, 256, 0, stream>>>(target_seq, init_input, Wih0, Whh0, bih0, bhh0,
                                  Wih1, Whh1, bih1, bhh1,
                                  xs, W0p, W1ip, W1hp, bias0, bias1, wv0);
  k_enc<<<64, 256, 0, stream>>>(physical, enc_W1, enc_b1, enc_ln1_g, enc_ln1_b,
                                enc_W2, enc_b2, enc_ln2_g, enc_ln2_b, h0enc);
  k_l0<<<64, 512, 0, stream>>>(W0p, bias0, wv0, xs, h0enc, o0pack);
  k_l1<<<64, 512, 0, stream>>>(W1ip, W1hp, bias1, o0pack, h0enc, h1store);
  k_head<<<4096, 256, 0, stream>>>(h1store, ln_g, ln_b, proj_W, proj_b,
                                   head_W1, head_b1, head_W2, head_b2, qout);
  k_blend<<<1, 512, 0, stream>>>(qout, (float*)d_out);
}

// Round 2
// 623.642 us; speedup vs baseline: 3.7902x; 3.7902x over previous
//
#include <hip/hip_runtime.h>
#include <hip/hip_bf16.h>

#define BB 512
#define TT 128

typedef unsigned short u16;
typedef short v8s __attribute__((ext_vector_type(8)));
typedef float f32x4 __attribute__((ext_vector_type(4)));

__device__ __forceinline__ u16 f2bf(float x){
  union { float f; unsigned int u; } v; v.f = x;
  unsigned int r = (v.u + 0x7fffu + ((v.u >> 16) & 1u)) >> 16;
  return (u16)r;
}
__device__ __forceinline__ float bf2f(u16 u){
  union { unsigned int i; float f; } v; v.i = ((unsigned int)u) << 16; return v.f;
}
__device__ __forceinline__ uint2 pack4(f32x4 a){
  uint2 r;
  r.x = (unsigned)f2bf(a[0]) | ((unsigned)f2bf(a[1]) << 16);
  r.y = (unsigned)f2bf(a[2]) | ((unsigned)f2bf(a[3]) << 16);
  return r;
}
__device__ __forceinline__ float sigm(float x){
  x = fminf(fmaxf(x, -30.f), 30.f);
  return 1.f / (1.f + __expf(-x));
}
__device__ __forceinline__ float tanh_f(float x){
  x = fminf(fmaxf(x, -15.f), 15.f);
  float e = __expf(-2.f * x);
  return (1.f - e) / (1.f + e);
}

// ---------------- prep: pack weights into MFMA-fragment order, build xs/biases ----
// frag layout convention (A and B identical): tile=j>>4, kf=k>>5,
//   lane=(j&15)+16*((k&31)>>3), elem=k&7.
__global__ __launch_bounds__(256) void k_prep(
    const float* tseq, const float* init_in,
    const float* Wih0, const float* Whh0, const float* bih0, const float* bhh0,
    const float* Wih1, const float* Whh1, const float* bih1, const float* bhh1,
    const float* projW, const float* hW1,
    float* xs, u16* W0p, u16* W1ip, u16* W1hp, u16* projWp, u16* hW1p,
    float* bias0, float* bias1, float* wv0)
{
  int tid = blockIdx.x * blockDim.x + threadIdx.x;
  int stride = gridDim.x * blockDim.x;
  for (int i = tid; i < TT*BB; i += stride){
    int t = i / BB, b = i % BB;
    xs[i] = (t == 0) ? init_in[0] : tseq[b*TT + (t-1)];
  }
  for (int i = tid; i < 2*512*128; i += stride){
    int d = i / (512*128), r = i % (512*128);
    int j = r / 128, k = r % 128;
    int dst = ((((d*32 + (j>>4))*4 + (k>>5))*64) + ((j&15) + 16*((k&31)>>3)))*8 + (k&7);
    W0p[dst]  = f2bf(Whh0[i]);
    W1hp[dst] = f2bf(Whh1[i]);
  }
  for (int i = tid; i < 2*512*256; i += stride){
    int d = i / (512*256), r = i % (512*256);
    int j = r / 256, k = r % 256;
    int dst = ((((d*32 + (j>>4))*8 + (k>>5))*64) + ((j&15) + 16*((k&31)>>3)))*8 + (k&7);
    W1ip[dst] = f2bf(Wih1[i]);
  }
  for (int i = tid; i < 128*256; i += stride){
    int j = i / 256, k = i % 256;
    int dst = ((((j>>4)*8 + (k>>5))*64) + ((j&15) + 16*((k&31)>>3)))*8 + (k&7);
    projWp[dst] = f2bf(projW[i]);
  }
  for (int i = tid; i < 128*128; i += stride){
    int j = i / 128, k = i % 128;
    int dst = ((((j>>4)*4 + (k>>5))*64) + ((j&15) + 16*((k&31)>>3)))*8 + (k&7);
    hW1p[dst] = f2bf(hW1[i]);
  }
  for (int i = tid; i < 2*512; i += stride){
    bias0[i] = bih0[i] + bhh0[i];
    bias1[i] = bih1[i] + bhh1[i];
    wv0[i]   = Wih0[i];
  }
}

// ---------------- encoder ---------------------------------------------------------
__global__ __launch_bounds__(256) void k_enc(
    const float* phys, const float* W1, const float* b1, const float* g1, const float* be1,
    const float* W2, const float* b2, const float* g2, const float* be2, float* h0enc)
{
  __shared__ float eL[8][256];
  int tid = threadIdx.x;
  int rr = tid >> 5, sub = tid & 31;
  int r = blockIdx.x * 8 + rr;
  float x[16];
#pragma unroll
  for (int k = 0; k < 16; ++k) x[k] = phys[r*16 + k];
  float y[8];
#pragma unroll
  for (int jj = 0; jj < 8; ++jj){
    int j = sub*8 + jj;
    float s = b1[j];
#pragma unroll
    for (int k = 0; k < 16; ++k) s += x[k] * W1[j*16 + k];
    y[jj] = s;
  }
  float sum = 0.f, sq = 0.f;
#pragma unroll
  for (int jj = 0; jj < 8; ++jj){ sum += y[jj]; sq += y[jj]*y[jj]; }
#pragma unroll
  for (int m = 16; m >= 1; m >>= 1){ sum += __shfl_xor(sum, m, 32); sq += __shfl_xor(sq, m, 32); }
  float mu = sum / 256.f;
  float rs = rsqrtf(sq / 256.f - mu*mu + 1e-5f);
#pragma unroll
  for (int jj = 0; jj < 8; ++jj){
    int j = sub*8 + jj;
    eL[rr][j] = fmaxf((y[jj] - mu) * rs * g1[j] + be1[j], 0.f);
  }
  __syncthreads();
  float y2[4];
#pragma unroll
  for (int jj = 0; jj < 4; ++jj){
    int j2 = sub*4 + jj;
    float s = b2[j2];
    const float* wrow = W2 + j2*256;
    for (int k = 0; k < 256; k += 4)
      s += eL[rr][k]*wrow[k] + eL[rr][k+1]*wrow[k+1] + eL[rr][k+2]*wrow[k+2] + eL[rr][k+3]*wrow[k+3];
    y2[jj] = s;
  }
  sum = 0.f; sq = 0.f;
#pragma unroll
  for (int jj = 0; jj < 4; ++jj){ sum += y2[jj]; sq += y2[jj]*y2[jj]; }
#pragma unroll
  for (int m = 16; m >= 1; m >>= 1){ sum += __shfl_xor(sum, m, 32); sq += __shfl_xor(sq, m, 32); }
  mu = sum / 128.f;
  rs = rsqrtf(sq / 128.f - mu*mu + 1e-5f);
#pragma unroll
  for (int jj = 0; jj < 4; ++jj){
    int j2 = sub*4 + jj;
    h0enc[r*128 + j2] = tanh_f((y2[jj]-mu)*rs*g2[j2] + be2[j2]);
  }
}

// ---------------- layer0 recurrence: weights live in VGPRs ------------------------
__global__ __launch_bounds__(512, 2) void k_l0(
    const u16* W0p, const float* bias0, const float* wv0, const float* xs,
    const float* h0enc, u16* o0pack)
{
  __shared__ __align__(16) u16 Xb[2][4][512];
  int bx = blockIdx.x;
  int tile = bx & 31, d = bx >> 5;
  int tid = threadIdx.x, w = tid >> 6, l = tid & 63;
  int r0 = tile * 16, lrow = l & 15, lk = l >> 4;

  if (tid < 256){
    int kf = tid >> 6, ll = tid & 63;
    const float* src = h0enc + (r0 + (ll & 15))*128 + kf*32 + 8*(ll >> 4);
    u16* dstp = &Xb[0][kf][ll*8];
#pragma unroll
    for (int i = 0; i < 8; ++i) dstp[i] = f2bf(src[i]);
  }

  const u16* Wb = W0p + (size_t)d*32*4*512;
  v8s wa[4][4];
#pragma unroll
  for (int q = 0; q < 4; ++q)
#pragma unroll
    for (int kf = 0; kf < 4; ++kf)
      wa[q][kf] = *(const v8s*)(Wb + (size_t)(((w + 8*q)*4 + kf)*64 + l)*8);

  float bias[4][4], wv[4][4];
#pragma unroll
  for (int q = 0; q < 4; ++q){
    int tq = w + 8*q;
#pragma unroll
    for (int jj = 0; jj < 4; ++jj){
      int j = tq*16 + 4*lk + jj;
      bias[q][jj] = bias0[d*512 + j];
      wv[q][jj]   = wv0[d*512 + j];
    }
  }
  float c[4] = {0.f,0.f,0.f,0.f};
  int jout = w*16 + 4*lk;
  int kfx = jout >> 5;
  int sl  = lrow + 16*((jout & 31) >> 3);
  int eb  = jout & 7;
  int kfo = 4*d + kfx;
  __syncthreads();

  for (int t = 0; t < TT; ++t){
    int cur = t & 1, nxt = cur ^ 1;
    v8s bfr[4];
#pragma unroll
    for (int kf = 0; kf < 4; ++kf) bfr[kf] = *(const v8s*)&Xb[cur][kf][l*8];
    f32x4 acc[4];
#pragma unroll
    for (int q = 0; q < 4; ++q) acc[q] = (f32x4){0.f,0.f,0.f,0.f};
#pragma unroll
    for (int kf = 0; kf < 4; ++kf)
#pragma unroll
      for (int q = 0; q < 4; ++q)
        acc[q] = __builtin_amdgcn_mfma_f32_16x16x32_bf16(wa[q][kf], bfr[kf], acc[q], 0, 0, 0);
    float xv = xs[t*BB + r0 + lrow];
    float hn[4];
#pragma unroll
    for (int jj = 0; jj < 4; ++jj){
      float gi = acc[0][jj] + bias[0][jj] + xv*wv[0][jj];
      float gf = acc[1][jj] + bias[1][jj] + xv*wv[1][jj];
      float gg = acc[2][jj] + bias[2][jj] + xv*wv[2][jj];
      float go = acc[3][jj] + bias[3][jj] + xv*wv[3][jj];
      float cn = sigm(gf)*c[jj] + sigm(gi)*tanh_f(gg);
      c[jj] = cn;
      hn[jj] = sigm(go)*tanh_f(cn);
    }
    uint2 hp;
    hp.x = (unsigned)f2bf(hn[0]) | ((unsigned)f2bf(hn[1]) << 16);
    hp.y = (unsigned)f2bf(hn[2]) | ((unsigned)f2bf(hn[3]) << 16);
    *(uint2*)&Xb[nxt][kfx][sl*8 + eb] = hp;
    size_t off = ((((size_t)t*32 + tile)*8 + kfo)*64 + sl)*8 + eb;
    *(uint2*)&o0pack[off] = hp;
    __syncthreads();
  }
}

// ---------------- Z1 = o0 @ Wih1^T for all t (parallel GEMM, bf16 out) ------------
// grid: t(128) x btile-group(8, 4 btiles ea.) x nchunk(4, 16 ntiles ea.)
__global__ __launch_bounds__(256) void k_zgemm(
    const u16* W1ip, const u16* o0pack, u16* z1p)
{
  int bx = blockIdx.x;
  int nc = bx & 3, bg = (bx >> 2) & 7, t = bx >> 5;
  int w = threadIdx.x >> 6, l = threadIdx.x & 63;
  int btile = bg*4 + w;
  v8s bfrag[8];
#pragma unroll
  for (int kf = 0; kf < 8; ++kf)
    bfrag[kf] = *(const v8s*)&o0pack[((((size_t)t*32 + btile)*8 + kf)*64 + l)*8];
  f32x4 acc[16];
#pragma unroll
  for (int nt = 0; nt < 16; ++nt) acc[nt] = (f32x4){0.f,0.f,0.f,0.f};
#pragma unroll
  for (int kf = 0; kf < 8; ++kf){
#pragma unroll
    for (int nt = 0; nt < 16; ++nt){
      int ntg = nc*16 + nt;
      int dir = ntg >> 5, tl = ntg & 31;
      v8s a = *(const v8s*)&W1ip[((((size_t)dir*32 + tl)*8 + kf)*64 + l)*8];
      acc[nt] = __builtin_amdgcn_mfma_f32_16x16x32_bf16(a, bfrag[kf], acc[nt], 0, 0, 0);
    }
  }
#pragma unroll
  for (int nt = 0; nt < 16; ++nt){
    int ntg = nc*16 + nt;
    uint2 zp = pack4(acc[nt]);
    *(uint2*)&z1p[((((size_t)t*32 + btile)*64 + ntg)*64 + l)*4] = zp;
  }
}

// ---------------- layer1 recurrence: Whh in VGPRs, Z1 prefetched ------------------
__global__ __launch_bounds__(512, 2) void k_l1(
    const u16* W1hp, const float* bias1, const u16* z1p,
    const float* h0enc, float* h1store)
{
  __shared__ __align__(16) u16 Xh[2][4][512];
  int bx = blockIdx.x;
  int tile = bx & 31, d = bx >> 5;
  int tid = threadIdx.x, w = tid >> 6, l = tid & 63;
  int r0 = tile * 16, lrow = l & 15, lk = l >> 4;

  if (tid < 256){
    int kf = tid >> 6, ll = tid & 63;
    const float* src = h0enc + (r0 + (ll & 15))*128 + kf*32 + 8*(ll >> 4);
    u16* dstp = &Xh[0][kf][ll*8];
#pragma unroll
    for (int i = 0; i < 8; ++i) dstp[i] = f2bf(src[i]);
  }

  const u16* Wh = W1hp + (size_t)d*32*4*512;
  v8s wh[4][4];
#pragma unroll
  for (int q = 0; q < 4; ++q)
#pragma unroll
    for (int kf = 0; kf < 4; ++kf)
      wh[q][kf] = *(const v8s*)(Wh + (size_t)(((w + 8*q)*4 + kf)*64 + l)*8);

  float bias[4][4];
#pragma unroll
  for (int q = 0; q < 4; ++q)
#pragma unroll
    for (int jj = 0; jj < 4; ++jj)
      bias[q][jj] = bias1[d*512 + (w + 8*q)*16 + 4*lk + jj];

  float c[4] = {0.f,0.f,0.f,0.f};
  int jout = w*16 + 4*lk;
  int kfx = jout >> 5;
  int sl  = lrow + 16*((jout & 31) >> 3);
  int eb  = jout & 7;

  uint2 zr[4];
#pragma unroll
  for (int q = 0; q < 4; ++q)
    zr[q] = *(const uint2*)&z1p[((((size_t)0*32 + tile)*64 + d*32 + w + 8*q)*64 + l)*4];
  __syncthreads();

  for (int t = 0; t < TT; ++t){
    int cur = t & 1, nxt = cur ^ 1;
    uint2 zn[4];
    if (t + 1 < TT){
#pragma unroll
      for (int q = 0; q < 4; ++q)
        zn[q] = *(const uint2*)&z1p[((((size_t)(t+1)*32 + tile)*64 + d*32 + w + 8*q)*64 + l)*4];
    }
    v8s bh[4];
#pragma unroll
    for (int kf = 0; kf < 4; ++kf) bh[kf] = *(const v8s*)&Xh[cur][kf][l*8];
    f32x4 acc[4];
#pragma unroll
    for (int q = 0; q < 4; ++q){
      acc[q][0] = bf2f((u16)(zr[q].x & 0xffffu));
      acc[q][1] = bf2f((u16)(zr[q].x >> 16));
      acc[q][2] = bf2f((u16)(zr[q].y & 0xffffu));
      acc[q][3] = bf2f((u16)(zr[q].y >> 16));
    }
#pragma unroll
    for (int kf = 0; kf < 4; ++kf)
#pragma unroll
      for (int q = 0; q < 4; ++q)
        acc[q] = __builtin_amdgcn_mfma_f32_16x16x32_bf16(wh[q][kf], bh[kf], acc[q], 0, 0, 0);
    float hn[4];
#pragma unroll
    for (int jj = 0; jj < 4; ++jj){
      float gi = acc[0][jj] + bias[0][jj];
      float gf = acc[1][jj] + bias[1][jj];
      float gg = acc[2][jj] + bias[2][jj];
      float go = acc[3][jj] + bias[3][jj];
      float cn = sigm(gf)*c[jj] + sigm(gi)*tanh_f(gg);
      c[jj] = cn;
      hn[jj] = sigm(go)*tanh_f(cn);
    }
    uint2 hp;
    hp.x = (unsigned)f2bf(hn[0]) | ((unsigned)f2bf(hn[1]) << 16);
    hp.y = (unsigned)f2bf(hn[2]) | ((unsigned)f2bf(hn[3]) << 16);
    *(uint2*)&Xh[nxt][kfx][sl*8 + eb] = hp;
    f32x4 hv = {hn[0], hn[1], hn[2], hn[3]};
    *(f32x4*)&h1store[((size_t)t*BB + r0 + lrow)*256 + d*128 + jout] = hv;
#pragma unroll
    for (int q = 0; q < 4; ++q) zr[q] = zn[q];
    __syncthreads();
  }
}

// ---------------- head: LN -> proj -> relu head1 -> head2 via MFMA ---------------
// block = 4 waves x 16 rows; per-wave LDS, no barriers.
__global__ __launch_bounds__(256) void k_head(
    const float* h1store, const float* lng, const float* lnb,
    const u16* projWp, const float* projb,
    const u16* hW1p, const float* hb1, const float* hW2, const float* hb2,
    float* qout)
{
  __shared__ __align__(16) u16 xls[4][16*256];  // 32 KB, swizzled
  __shared__ __align__(16) u16 pls[4][16*128];  // 16 KB, swizzled
  int w = threadIdx.x >> 6, l = threadIdx.x & 63;
  size_t g0 = (size_t)blockIdx.x*64 + w*16;
  int row = l >> 2, qc = l & 3;

  // load 16 rows x 256, LN in f32, pack bf16 into swizzled LDS
  const float* src = h1store + (g0 + row)*256;
  f32x4 v[16];
#pragma unroll
  for (int m = 0; m < 16; ++m) v[m] = *(const f32x4*)&src[m*16 + qc*4];
  float sum = 0.f, sq = 0.f;
#pragma unroll
  for (int m = 0; m < 16; ++m){
#pragma unroll
    for (int i = 0; i < 4; ++i){ sum += v[m][i]; sq += v[m][i]*v[m][i]; }
  }
  sum += __shfl_xor(sum, 1); sq += __shfl_xor(sq, 1);
  sum += __shfl_xor(sum, 2); sq += __shfl_xor(sq, 2);
  float mu = sum / 256.f;
  float rs = rsqrtf(sq / 256.f - mu*mu + 1e-5f);
  u16* xw = xls[w];
  int rsw = (row & 7) << 3;    // 16B-granule XOR swizzle, u16 units
#pragma unroll
  for (int m = 0; m < 16; ++m){
    int cb = m*16 + qc*4;
    f32x4 gq = *(const f32x4*)&lng[cb];
    f32x4 bq = *(const f32x4*)&lnb[cb];
    f32x4 xn;
#pragma unroll
    for (int i = 0; i < 4; ++i) xn[i] = (v[m][i]-mu)*rs*gq[i] + bq[i];
    *(uint2*)&xw[(row*256 + cb) ^ rsw] = pack4(xn);
  }

  // proj: (16x256)@(256x128) MFMA
  int lk = l >> 4, r = l & 15;
  int rsw2 = (r & 7) << 3;
  f32x4 acc[8];
#pragma unroll
  for (int nt = 0; nt < 8; ++nt) acc[nt] = *(const f32x4*)&projb[nt*16 + lk*4];
#pragma unroll
  for (int kf = 0; kf < 8; ++kf){
    v8s b = *(const v8s*)&xw[(r*256 + kf*32 + lk*8) ^ rsw2];
#pragma unroll
    for (int nt = 0; nt < 8; ++nt){
      v8s a = *(const v8s*)&projWp[(((size_t)nt*8 + kf)*64 + l)*8];
      acc[nt] = __builtin_amdgcn_mfma_f32_16x16x32_bf16(a, b, acc[nt], 0, 0, 0);
    }
  }
  u16* pw = pls[w];
#pragma unroll
  for (int nt = 0; nt < 8; ++nt)
    *(uint2*)&pw[(r*128 + nt*16 + lk*4) ^ rsw2] = pack4(acc[nt]);

  // head1: (16x128)@(128x128) MFMA
  f32x4 acc2[8];
#pragma unroll
  for (int nt = 0; nt < 8; ++nt) acc2[nt] = *(const f32x4*)&hb1[nt*16 + lk*4];
#pragma unroll
  for (int kf = 0; kf < 4; ++kf){
    v8s b = *(const v8s*)&pw[(r*128 + kf*32 + lk*8) ^ rsw2];
#pragma unroll
    for (int nt = 0; nt < 8; ++nt){
      v8s a = *(const v8s*)&hW1p[(((size_t)nt*4 + kf)*64 + l)*8];
      acc2[nt] = __builtin_amdgcn_mfma_f32_16x16x32_bf16(a, b, acc2[nt], 0, 0, 0);
    }
  }
  // head2: relu + dot with hW2, reduce lanes sharing r
  float part = 0.f;
#pragma unroll
  for (int nt = 0; nt < 8; ++nt){
    f32x4 w2 = *(const f32x4*)&hW2[nt*16 + lk*4];
#pragma unroll
    for (int jj = 0; jj < 4; ++jj) part += fmaxf(acc2[nt][jj], 0.f) * w2[jj];
  }
  part += __shfl_xor(part, 16);
  part += __shfl_xor(part, 32);
  if (l < 16) qout[g0 + l] = part + hb2[0];
}

// ---------------- AR blend --------------------------------------------------------
__global__ __launch_bounds__(512) void k_blend(const float* qout, float* out)
{
  int b = threadIdx.x;
  float pred = 0.f;
  for (int t0 = 0; t0 < TT; t0 += 16){
    float v[16];
#pragma unroll
    for (int i = 0; i < 16; ++i) v[i] = qout[(t0+i)*BB + b];
#pragma unroll
    for (int i = 0; i < 16; ++i){
      pred = (t0 + i == 0) ? v[i] : 0.8f*v[i] + 0.2f*pred;
      out[b*TT + t0 + i] = pred;
    }
  }
}

extern "C" void kernel_launch(void* const* d_in, const int* in_sizes, int n_in,
                              void* d_out, int out_size, void* d_ws, size_t ws_size,
                              hipStream_t stream) {
  const float* physical   = (const float*)d_in[0];
  const float* target_seq = (const float*)d_in[1];
  const float* enc_W1     = (const float*)d_in[2];
  const float* enc_b1     = (const float*)d_in[3];
  const float* enc_ln1_g  = (const float*)d_in[4];
  const float* enc_ln1_b  = (const float*)d_in[5];
  const float* enc_W2     = (const float*)d_in[6];
  const float* enc_b2     = (const float*)d_in[7];
  const float* enc_ln2_g  = (const float*)d_in[8];
  const float* enc_ln2_b  = (const float*)d_in[9];
  const float* Wih0       = (const float*)d_in[10];
  const float* Whh0       = (const float*)d_in[11];
  const float* bih0       = (const float*)d_in[12];
  const float* bhh0       = (const float*)d_in[13];
  const float* Wih1       = (const float*)d_in[14];
  const float* Whh1       = (const float*)d_in[15];
  const float* bih1       = (const float*)d_in[16];
  const float* bhh1       = (const float*)d_in[17];
  const float* ln_g       = (const float*)d_in[18];
  const float* ln_b       = (const float*)d_in[19];
  const float* proj_W     = (const float*)d_in[20];
  const float* proj_b     = (const float*)d_in[21];
  const float* head_W1    = (const float*)d_in[22];
  const float* head_b1    = (const float*)d_in[23];
  const float* head_W2    = (const float*)d_in[24];
  const float* head_b2    = (const float*)d_in[25];
  const float* init_input = (const float*)d_in[26];

  size_t off = 0;
  char* base = (char*)d_ws;
  auto carve = [&](size_t bytes) -> void* {
    void* p = base + off;
    off += (bytes + 255) & ~(size_t)255;
    return p;
  };
  u16*   o0pack  = (u16*)  carve((size_t)TT*32*8*64*8*2);     // 32 MB bf16 frag-packed
  float* h1store = (float*)carve((size_t)TT*BB*256*4);        // 64 MB f32
  u16*   z1p     = (u16*)  carve((size_t)TT*32*64*64*4*2);    // 128 MB bf16 C-frag
  float* qout    = (float*)carve((size_t)TT*BB*4);
  float* h0enc   = (float*)carve((size_t)BB*128*4);
  float* xs      = (float*)carve((size_t)TT*BB*4);
  u16*   W0p     = (u16*)  carve((size_t)2*512*128*2);
  u16*   W1ip    = (u16*)  carve((size_t)2*512*256*2);
  u16*   W1hp    = (u16*)  carve((size_t)2*512*128*2);
  u16*   projWp  = (u16*)  carve((size_t)128*256*2);
  u16*   hW1p    = (u16*)  carve((size_t)128*128*2);
  float* bias0   = (float*)carve(4096);
  float* bias1   = (float*)carve(4096);
  float* wv0     = (float*)carve(4096);

  k_prep<<<256, 256, 0, stream>>>(target_seq, init_input, Wih0, Whh0, bih0, bhh0,
                                  Wih1, Whh1, bih1, bhh1, proj_W, head_W1,
                                  xs, W0p, W1ip, W1hp, projWp, hW1p,
                                  bias0, bias1, wv0);
  k_enc<<<64, 256, 0, stream>>>(physical, enc_W1, enc_b1, enc_ln1_g, enc_ln1_b,
                                enc_W2, enc_b2, enc_ln2_g, enc_ln2_b, h0enc);
  k_l0<<<64, 512, 0, stream>>>(W0p, bias0, wv0, xs, h0enc, o0pack);
  k_zgemm<<<4096, 256, 0, stream>>>(W1ip, o0pack, z1p);
  k_l1<<<64, 512, 0, stream>>>(W1hp, bias1, z1p, h0enc, h1store);
  k_head<<<1024, 256, 0, stream>>>(h1store, ln_g, ln_b, projWp, proj_b,
                                   hW1p, head_b1, head_W2, head_b2, qout);
  k_blend<<<1, 512, 0, stream>>>(qout, (float*)d_out);
}

// Round 3
// 428.338 us; speedup vs baseline: 5.5183x; 1.4560x over previous
//
#include <hip/hip_runtime.h>
#include <hip/hip_bf16.h>

#define BB 512
#define TT 128

typedef unsigned short u16;
typedef short v8s __attribute__((ext_vector_type(8)));
typedef float f32x4 __attribute__((ext_vector_type(4)));

__device__ __forceinline__ u16 f2bf(float x){
  union { float f; unsigned int u; } v; v.f = x;
  unsigned int r = (v.u + 0x7fffu + ((v.u >> 16) & 1u)) >> 16;
  return (u16)r;
}
__device__ __forceinline__ float bf2f(u16 u){
  union { unsigned int i; float f; } v; v.i = ((unsigned int)u) << 16; return v.f;
}
__device__ __forceinline__ uint2 pack4(f32x4 a){
  uint2 r;
  r.x = (unsigned)f2bf(a[0]) | ((unsigned)f2bf(a[1]) << 16);
  r.y = (unsigned)f2bf(a[2]) | ((unsigned)f2bf(a[3]) << 16);
  return r;
}
__device__ __forceinline__ float rcp_f(float x){ return __builtin_amdgcn_rcpf(x); }
// clamp-free: x->-inf: exp(+inf)=inf, rcp(inf)=0 ; x->+inf: exp->0 -> 1
__device__ __forceinline__ float sigm(float x){
  return rcp_f(1.f + __expf(-x));
}
// abs-trick: no NaN at x->-inf, clamps removed
__device__ __forceinline__ float tanh_f(float x){
  float e = __expf(-2.f * fabsf(x));
  float r = (1.f - e) * rcp_f(1.f + e);
  return copysignf(r, x);
}
// barrier that waits only LDS ops: global stores/loads stay in flight
__device__ __forceinline__ void bar_lds(){
  __builtin_amdgcn_sched_barrier(0);
  asm volatile("s_waitcnt lgkmcnt(0)" ::: "memory");
  __builtin_amdgcn_s_barrier();
  __builtin_amdgcn_sched_barrier(0);
}

// ---------------- prep: pack weights into MFMA-fragment order, build xs/biases ----
// frag layout convention (A and B identical): tile=j>>4, kf=k>>5,
//   lane=(j&15)+16*((k&31)>>3), elem=k&7.
__global__ __launch_bounds__(256) void k_prep(
    const float* tseq, const float* init_in,
    const float* Wih0, const float* Whh0, const float* bih0, const float* bhh0,
    const float* Wih1, const float* Whh1, const float* bih1, const float* bhh1,
    const float* projW, const float* hW1,
    float* xs, u16* W0p, u16* W1ip, u16* W1hp, u16* projWp, u16* hW1p,
    float* bias0, float* bias1, float* wv0)
{
  int tid = blockIdx.x * blockDim.x + threadIdx.x;
  int stride = gridDim.x * blockDim.x;
  for (int i = tid; i < TT*BB; i += stride){
    int t = i / BB, b = i % BB;
    xs[i] = (t == 0) ? init_in[0] : tseq[b*TT + (t-1)];
  }
  for (int i = tid; i < 2*512*128; i += stride){
    int d = i / (512*128), r = i % (512*128);
    int j = r / 128, k = r % 128;
    int dst = ((((d*32 + (j>>4))*4 + (k>>5))*64) + ((j&15) + 16*((k&31)>>3)))*8 + (k&7);
    W0p[dst]  = f2bf(Whh0[i]);
    W1hp[dst] = f2bf(Whh1[i]);
  }
  for (int i = tid; i < 2*512*256; i += stride){
    int d = i / (512*256), r = i % (512*256);
    int j = r / 256, k = r % 256;
    int dst = ((((d*32 + (j>>4))*8 + (k>>5))*64) + ((j&15) + 16*((k&31)>>3)))*8 + (k&7);
    W1ip[dst] = f2bf(Wih1[i]);
  }
  for (int i = tid; i < 128*256; i += stride){
    int j = i / 256, k = i % 256;
    int dst = ((((j>>4)*8 + (k>>5))*64) + ((j&15) + 16*((k&31)>>3)))*8 + (k&7);
    projWp[dst] = f2bf(projW[i]);
  }
  for (int i = tid; i < 128*128; i += stride){
    int j = i / 128, k = i % 128;
    int dst = ((((j>>4)*4 + (k>>5))*64) + ((j&15) + 16*((k&31)>>3)))*8 + (k&7);
    hW1p[dst] = f2bf(hW1[i]);
  }
  for (int i = tid; i < 2*512; i += stride){
    bias0[i] = bih0[i] + bhh0[i];
    bias1[i] = bih1[i] + bhh1[i];
    wv0[i]   = Wih0[i];
  }
}

// ---------------- encoder ---------------------------------------------------------
__global__ __launch_bounds__(256) void k_enc(
    const float* phys, const float* W1, const float* b1, const float* g1, const float* be1,
    const float* W2, const float* b2, const float* g2, const float* be2, float* h0enc)
{
  __shared__ float eL[8][256];
  int tid = threadIdx.x;
  int rr = tid >> 5, sub = tid & 31;
  int r = blockIdx.x * 8 + rr;
  float x[16];
#pragma unroll
  for (int k = 0; k < 16; ++k) x[k] = phys[r*16 + k];
  float y[8];
#pragma unroll
  for (int jj = 0; jj < 8; ++jj){
    int j = sub*8 + jj;
    float s = b1[j];
#pragma unroll
    for (int k = 0; k < 16; ++k) s += x[k] * W1[j*16 + k];
    y[jj] = s;
  }
  float sum = 0.f, sq = 0.f;
#pragma unroll
  for (int jj = 0; jj < 8; ++jj){ sum += y[jj]; sq += y[jj]*y[jj]; }
#pragma unroll
  for (int m = 16; m >= 1; m >>= 1){ sum += __shfl_xor(sum, m, 32); sq += __shfl_xor(sq, m, 32); }
  float mu = sum / 256.f;
  float rs = rsqrtf(sq / 256.f - mu*mu + 1e-5f);
#pragma unroll
  for (int jj = 0; jj < 8; ++jj){
    int j = sub*8 + jj;
    eL[rr][j] = fmaxf((y[jj] - mu) * rs * g1[j] + be1[j], 0.f);
  }
  __syncthreads();
  float y2[4];
#pragma unroll
  for (int jj = 0; jj < 4; ++jj){
    int j2 = sub*4 + jj;
    float s = b2[j2];
    const float* wrow = W2 + j2*256;
    for (int k = 0; k < 256; k += 4)
      s += eL[rr][k]*wrow[k] + eL[rr][k+1]*wrow[k+1] + eL[rr][k+2]*wrow[k+2] + eL[rr][k+3]*wrow[k+3];
    y2[jj] = s;
  }
  sum = 0.f; sq = 0.f;
#pragma unroll
  for (int jj = 0; jj < 4; ++jj){ sum += y2[jj]; sq += y2[jj]*y2[jj]; }
#pragma unroll
  for (int m = 16; m >= 1; m >>= 1){ sum += __shfl_xor(sum, m, 32); sq += __shfl_xor(sq, m, 32); }
  mu = sum / 128.f;
  rs = rsqrtf(sq / 128.f - mu*mu + 1e-5f);
#pragma unroll
  for (int jj = 0; jj < 4; ++jj){
    int j2 = sub*4 + jj;
    h0enc[r*128 + j2] = tanh_f((y2[jj]-mu)*rs*g2[j2] + be2[j2]);
  }
}

// ---------------- layer0 recurrence: weights in VGPRs, xs in LDS, lgkm-barrier ----
__global__ __launch_bounds__(512, 2) void k_l0(
    const u16* W0p, const float* bias0, const float* wv0, const float* xs,
    const float* h0enc, u16* o0pack)
{
  __shared__ __align__(16) u16 Xb[2][4][512];
  __shared__ __align__(16) float xl[TT*16];
  int bx = blockIdx.x;
  int tile = bx & 31, d = bx >> 5;
  int tid = threadIdx.x, w = tid >> 6, l = tid & 63;
  int r0 = tile * 16, lrow = l & 15, lk = l >> 4;

  for (int i = tid; i < TT*16; i += 512){
    int t = i >> 4, r = i & 15;
    xl[i] = xs[t*BB + r0 + r];
  }
  if (tid < 256){
    int kf = tid >> 6, ll = tid & 63;
    const float* src = h0enc + (r0 + (ll & 15))*128 + kf*32 + 8*(ll >> 4);
    u16* dstp = &Xb[0][kf][ll*8];
#pragma unroll
    for (int i = 0; i < 8; ++i) dstp[i] = f2bf(src[i]);
  }

  const u16* Wb = W0p + (size_t)d*32*4*512;
  v8s wa[4][4];
#pragma unroll
  for (int q = 0; q < 4; ++q)
#pragma unroll
    for (int kf = 0; kf < 4; ++kf)
      wa[q][kf] = *(const v8s*)(Wb + (size_t)(((w + 8*q)*4 + kf)*64 + l)*8);

  float bias[4][4], wv[4][4];
#pragma unroll
  for (int q = 0; q < 4; ++q){
    int tq = w + 8*q;
#pragma unroll
    for (int jj = 0; jj < 4; ++jj){
      int j = tq*16 + 4*lk + jj;
      bias[q][jj] = bias0[d*512 + j];
      wv[q][jj]   = wv0[d*512 + j];
    }
  }
  float c[4] = {0.f,0.f,0.f,0.f};
  int jout = w*16 + 4*lk;
  int kfx = jout >> 5;
  int sl  = lrow + 16*((jout & 31) >> 3);
  int eb  = jout & 7;
  int kfo = 4*d + kfx;
  __syncthreads();

  for (int t = 0; t < TT; ++t){
    int cur = t & 1, nxt = cur ^ 1;
    v8s bfr[4];
#pragma unroll
    for (int kf = 0; kf < 4; ++kf) bfr[kf] = *(const v8s*)&Xb[cur][kf][l*8];
    float xv = xl[t*16 + lrow];
    f32x4 acc[4];
#pragma unroll
    for (int q = 0; q < 4; ++q)
#pragma unroll
      for (int jj = 0; jj < 4; ++jj)
        acc[q][jj] = fmaf(xv, wv[q][jj], bias[q][jj]);   // bias + x*Wih folded into C
#pragma unroll
    for (int kf = 0; kf < 4; ++kf)
#pragma unroll
      for (int q = 0; q < 4; ++q)
        acc[q] = __builtin_amdgcn_mfma_f32_16x16x32_bf16(wa[q][kf], bfr[kf], acc[q], 0, 0, 0);
    float hn[4];
#pragma unroll
    for (int jj = 0; jj < 4; ++jj){
      float si = sigm(acc[0][jj]);
      float sf = sigm(acc[1][jj]);
      float tg = tanh_f(acc[2][jj]);
      float so = sigm(acc[3][jj]);
      float cn = fmaf(sf, c[jj], si*tg);
      c[jj] = cn;
      hn[jj] = so * tanh_f(cn);
    }
    uint2 hp;
    hp.x = (unsigned)f2bf(hn[0]) | ((unsigned)f2bf(hn[1]) << 16);
    hp.y = (unsigned)f2bf(hn[2]) | ((unsigned)f2bf(hn[3]) << 16);
    *(uint2*)&Xb[nxt][kfx][sl*8 + eb] = hp;
    size_t off = ((((size_t)t*32 + tile)*8 + kfo)*64 + sl)*8 + eb;
    *(uint2*)&o0pack[off] = hp;     // fire-and-forget: barrier below waits LDS only
    bar_lds();
  }
}

// ---------------- Z1 = o0 @ Wih1^T for all t (parallel GEMM, bf16 out) ------------
__global__ __launch_bounds__(256) void k_zgemm(
    const u16* W1ip, const u16* o0pack, u16* z1p)
{
  int bx = blockIdx.x;
  int nc = bx & 3, bg = (bx >> 2) & 7, t = bx >> 5;
  int w = threadIdx.x >> 6, l = threadIdx.x & 63;
  int btile = bg*4 + w;
  v8s bfrag[8];
#pragma unroll
  for (int kf = 0; kf < 8; ++kf)
    bfrag[kf] = *(const v8s*)&o0pack[((((size_t)t*32 + btile)*8 + kf)*64 + l)*8];
  f32x4 acc[16];
#pragma unroll
  for (int nt = 0; nt < 16; ++nt) acc[nt] = (f32x4){0.f,0.f,0.f,0.f};
#pragma unroll
  for (int kf = 0; kf < 8; ++kf){
#pragma unroll
    for (int nt = 0; nt < 16; ++nt){
      int ntg = nc*16 + nt;
      int dir = ntg >> 5, tl = ntg & 31;
      v8s a = *(const v8s*)&W1ip[((((size_t)dir*32 + tl)*8 + kf)*64 + l)*8];
      acc[nt] = __builtin_amdgcn_mfma_f32_16x16x32_bf16(a, bfrag[kf], acc[nt], 0, 0, 0);
    }
  }
#pragma unroll
  for (int nt = 0; nt < 16; ++nt){
    int ntg = nc*16 + nt;
    uint2 zp = pack4(acc[nt]);
    *(uint2*)&z1p[((((size_t)t*32 + btile)*64 + ntg)*64 + l)*4] = zp;
  }
}

// ---------------- layer1 recurrence: Whh in VGPRs, Z1 prefetched, lgkm-barrier ----
__global__ __launch_bounds__(512, 2) void k_l1(
    const u16* W1hp, const float* bias1, const u16* z1p,
    const float* h0enc, u16* h1b)
{
  __shared__ __align__(16) u16 Xh[2][4][512];
  int bx = blockIdx.x;
  int tile = bx & 31, d = bx >> 5;
  int tid = threadIdx.x, w = tid >> 6, l = tid & 63;
  int r0 = tile * 16, lrow = l & 15, lk = l >> 4;

  if (tid < 256){
    int kf = tid >> 6, ll = tid & 63;
    const float* src = h0enc + (r0 + (ll & 15))*128 + kf*32 + 8*(ll >> 4);
    u16* dstp = &Xh[0][kf][ll*8];
#pragma unroll
    for (int i = 0; i < 8; ++i) dstp[i] = f2bf(src[i]);
  }

  const u16* Wh = W1hp + (size_t)d*32*4*512;
  v8s wh[4][4];
#pragma unroll
  for (int q = 0; q < 4; ++q)
#pragma unroll
    for (int kf = 0; kf < 4; ++kf)
      wh[q][kf] = *(const v8s*)(Wh + (size_t)(((w + 8*q)*4 + kf)*64 + l)*8);

  float bias[4][4];
#pragma unroll
  for (int q = 0; q < 4; ++q)
#pragma unroll
    for (int jj = 0; jj < 4; ++jj)
      bias[q][jj] = bias1[d*512 + (w + 8*q)*16 + 4*lk + jj];

  float c[4] = {0.f,0.f,0.f,0.f};
  int jout = w*16 + 4*lk;
  int kfx = jout >> 5;
  int sl  = lrow + 16*((jout & 31) >> 3);
  int eb  = jout & 7;

  uint2 zr[4];
#pragma unroll
  for (int q = 0; q < 4; ++q)
    zr[q] = *(const uint2*)&z1p[(((size_t)tile*64 + d*32 + w + 8*q)*64 + l)*4];
  __syncthreads();

  for (int t = 0; t < TT; ++t){
    int cur = t & 1, nxt = cur ^ 1;
    int tn = (t + 1 < TT) ? t + 1 : t;
    uint2 zn[4];
#pragma unroll
    for (int q = 0; q < 4; ++q)
      zn[q] = *(const uint2*)&z1p[((((size_t)tn*32 + tile)*64 + d*32 + w + 8*q)*64 + l)*4];
    v8s bh[4];
#pragma unroll
    for (int kf = 0; kf < 4; ++kf) bh[kf] = *(const v8s*)&Xh[cur][kf][l*8];
    f32x4 acc[4];
#pragma unroll
    for (int q = 0; q < 4; ++q){
      acc[q][0] = bias[q][0] + bf2f((u16)(zr[q].x & 0xffffu));
      acc[q][1] = bias[q][1] + bf2f((u16)(zr[q].x >> 16));
      acc[q][2] = bias[q][2] + bf2f((u16)(zr[q].y & 0xffffu));
      acc[q][3] = bias[q][3] + bf2f((u16)(zr[q].y >> 16));
    }
#pragma unroll
    for (int kf = 0; kf < 4; ++kf)
#pragma unroll
      for (int q = 0; q < 4; ++q)
        acc[q] = __builtin_amdgcn_mfma_f32_16x16x32_bf16(wh[q][kf], bh[kf], acc[q], 0, 0, 0);
    float hn[4];
#pragma unroll
    for (int jj = 0; jj < 4; ++jj){
      float si = sigm(acc[0][jj]);
      float sf = sigm(acc[1][jj]);
      float tg = tanh_f(acc[2][jj]);
      float so = sigm(acc[3][jj]);
      float cn = fmaf(sf, c[jj], si*tg);
      c[jj] = cn;
      hn[jj] = so * tanh_f(cn);
    }
    uint2 hp;
    hp.x = (unsigned)f2bf(hn[0]) | ((unsigned)f2bf(hn[1]) << 16);
    hp.y = (unsigned)f2bf(hn[2]) | ((unsigned)f2bf(hn[3]) << 16);
    *(uint2*)&Xh[nxt][kfx][sl*8 + eb] = hp;
    int hidx = ((t*BB + r0 + lrow) << 8) + (d << 7) + jout;
    *(uint2*)&h1b[hidx] = hp;       // bf16 h1, fire-and-forget
#pragma unroll
    for (int q = 0; q < 4; ++q) zr[q] = zn[q];
    bar_lds();
  }
}

// ---------------- head: LN -> proj -> relu head1 -> head2 via MFMA ---------------
// block = 4 waves x 16 rows; per-wave LDS, no barriers. h1 input is bf16.
__global__ __launch_bounds__(256) void k_head(
    const u16* h1b, const float* lng, const float* lnb,
    const u16* projWp, const float* projb,
    const u16* hW1p, const float* hb1, const float* hW2, const float* hb2,
    float* qout)
{
  __shared__ __align__(16) u16 xls[4][16*256];  // 32 KB, swizzled
  __shared__ __align__(16) u16 pls[4][16*128];  // 16 KB, swizzled
  int w = threadIdx.x >> 6, l = threadIdx.x & 63;
  size_t g0 = (size_t)blockIdx.x*64 + w*16;
  int row = l >> 2, qc = l & 3;

  const u16* srcb = h1b + (g0 + row)*256;
  f32x4 v[16];
#pragma unroll
  for (int m = 0; m < 16; ++m){
    uint2 p = *(const uint2*)&srcb[m*16 + qc*4];
    v[m][0] = bf2f((u16)(p.x & 0xffffu));
    v[m][1] = bf2f((u16)(p.x >> 16));
    v[m][2] = bf2f((u16)(p.y & 0xffffu));
    v[m][3] = bf2f((u16)(p.y >> 16));
  }
  float sum = 0.f, sq = 0.f;
#pragma unroll
  for (int m = 0; m < 16; ++m){
#pragma unroll
    for (int i = 0; i < 4; ++i){ sum += v[m][i]; sq += v[m][i]*v[m][i]; }
  }
  sum += __shfl_xor(sum, 1); sq += __shfl_xor(sq, 1);
  sum += __shfl_xor(sum, 2); sq += __shfl_xor(sq, 2);
  float mu = sum / 256.f;
  float rs = rsqrtf(sq / 256.f - mu*mu + 1e-5f);
  u16* xw = xls[w];
  int rsw = (row & 7) << 3;    // 16B-granule XOR swizzle, u16 units
#pragma unroll
  for (int m = 0; m < 16; ++m){
    int cb = m*16 + qc*4;
    f32x4 gq = *(const f32x4*)&lng[cb];
    f32x4 bq = *(const f32x4*)&lnb[cb];
    f32x4 xn;
#pragma unroll
    for (int i = 0; i < 4; ++i) xn[i] = (v[m][i]-mu)*rs*gq[i] + bq[i];
    *(uint2*)&xw[(row*256 + cb) ^ rsw] = pack4(xn);
  }

  // proj: (16x256)@(256x128) MFMA
  int lk = l >> 4, r = l & 15;
  int rsw2 = (r & 7) << 3;
  f32x4 acc[8];
#pragma unroll
  for (int nt = 0; nt < 8; ++nt) acc[nt] = *(const f32x4*)&projb[nt*16 + lk*4];
#pragma unroll
  for (int kf = 0; kf < 8; ++kf){
    v8s b = *(const v8s*)&xw[(r*256 + kf*32 + lk*8) ^ rsw2];
#pragma unroll
    for (int nt = 0; nt < 8; ++nt){
      v8s a = *(const v8s*)&projWp[(((size_t)nt*8 + kf)*64 + l)*8];
      acc[nt] = __builtin_amdgcn_mfma_f32_16x16x32_bf16(a, b, acc[nt], 0, 0, 0);
    }
  }
  u16* pw = pls[w];
#pragma unroll
  for (int nt = 0; nt < 8; ++nt)
    *(uint2*)&pw[(r*128 + nt*16 + lk*4) ^ rsw2] = pack4(acc[nt]);

  // head1: (16x128)@(128x128) MFMA
  f32x4 acc2[8];
#pragma unroll
  for (int nt = 0; nt < 8; ++nt) acc2[nt] = *(const f32x4*)&hb1[nt*16 + lk*4];
#pragma unroll
  for (int kf = 0; kf < 4; ++kf){
    v8s b = *(const v8s*)&pw[(r*128 + kf*32 + lk*8) ^ rsw2];
#pragma unroll
    for (int nt = 0; nt < 8; ++nt){
      v8s a = *(const v8s*)&hW1p[(((size_t)nt*4 + kf)*64 + l)*8];
      acc2[nt] = __builtin_amdgcn_mfma_f32_16x16x32_bf16(a, b, acc2[nt], 0, 0, 0);
    }
  }
  // head2: relu + dot with hW2, reduce lanes sharing r
  float part = 0.f;
#pragma unroll
  for (int nt = 0; nt < 8; ++nt){
    f32x4 w2 = *(const f32x4*)&hW2[nt*16 + lk*4];
#pragma unroll
    for (int jj = 0; jj < 4; ++jj) part += fmaxf(acc2[nt][jj], 0.f) * w2[jj];
  }
  part += __shfl_xor(part, 16);
  part += __shfl_xor(part, 32);
  if (l < 16) qout[g0 + l] = part + hb2[0];
}

// ---------------- AR blend --------------------------------------------------------
__global__ __launch_bounds__(512) void k_blend(const float* qout, float* out)
{
  int b = threadIdx.x;
  float pred = 0.f;
  for (int t0 = 0; t0 < TT; t0 += 16){
    float v[16];
#pragma unroll
    for (int i = 0; i < 16; ++i) v[i] = qout[(t0+i)*BB + b];
#pragma unroll
    for (int i = 0; i < 16; ++i){
      pred = (t0 + i == 0) ? v[i] : 0.8f*v[i] + 0.2f*pred;
      out[b*TT + t0 + i] = pred;
    }
  }
}

extern "C" void kernel_launch(void* const* d_in, const int* in_sizes, int n_in,
                              void* d_out, int out_size, void* d_ws, size_t ws_size,
                              hipStream_t stream) {
  const float* physical   = (const float*)d_in[0];
  const float* target_seq = (const float*)d_in[1];
  const float* enc_W1     = (const float*)d_in[2];
  const float* enc_b1     = (const float*)d_in[3];
  const float* enc_ln1_g  = (const float*)d_in[4];
  const float* enc_ln1_b  = (const float*)d_in[5];
  const float* enc_W2     = (const float*)d_in[6];
  const float* enc_b2     = (const float*)d_in[7];
  const float* enc_ln2_g  = (const float*)d_in[8];
  const float* enc_ln2_b  = (const float*)d_in[9];
  const float* Wih0       = (const float*)d_in[10];
  const float* Whh0       = (const float*)d_in[11];
  const float* bih0       = (const float*)d_in[12];
  const float* bhh0       = (const float*)d_in[13];
  const float* Wih1       = (const float*)d_in[14];
  const float* Whh1       = (const float*)d_in[15];
  const float* bih1       = (const float*)d_in[16];
  const float* bhh1       = (const float*)d_in[17];
  const float* ln_g       = (const float*)d_in[18];
  const float* ln_b       = (const float*)d_in[19];
  const float* proj_W     = (const float*)d_in[20];
  const float* proj_b     = (const float*)d_in[21];
  const float* head_W1    = (const float*)d_in[22];
  const float* head_b1    = (const float*)d_in[23];
  const float* head_W2    = (const float*)d_in[24];
  const float* head_b2    = (const float*)d_in[25];
  const float* init_input = (const float*)d_in[26];

  size_t off = 0;
  char* base = (char*)d_ws;
  auto carve = [&](size_t bytes) -> void* {
    void* p = base + off;
    off += (bytes + 255) & ~(size_t)255;
    return p;
  };
  u16*   o0pack  = (u16*)  carve((size_t)TT*32*8*64*8*2);     // 32 MB bf16 frag-packed
  u16*   h1b     = (u16*)  carve((size_t)TT*BB*256*2);        // 32 MB bf16
  u16*   z1p     = (u16*)  carve((size_t)TT*32*64*64*4*2);    // 128 MB bf16 C-frag
  float* qout    = (float*)carve((size_t)TT*BB*4);
  float* h0enc   = (float*)carve((size_t)BB*128*4);
  float* xs      = (float*)carve((size_t)TT*BB*4);
  u16*   W0p     = (u16*)  carve((size_t)2*512*128*2);
  u16*   W1ip    = (u16*)  carve((size_t)2*512*256*2);
  u16*   W1hp    = (u16*)  carve((size_t)2*512*128*2);
  u16*   projWp  = (u16*)  carve((size_t)128*256*2);
  u16*   hW1p    = (u16*)  carve((size_t)128*128*2);
  float* bias0   = (float*)carve(4096);
  float* bias1   = (float*)carve(4096);
  float* wv0     = (float*)carve(4096);

  k_prep<<<256, 256, 0, stream>>>(target_seq, init_input, Wih0, Whh0, bih0, bhh0,
                                  Wih1, Whh1, bih1, bhh1, proj_W, head_W1,
                                  xs, W0p, W1ip, W1hp, projWp, hW1p,
                                  bias0, bias1, wv0);
  k_enc<<<64, 256, 0, stream>>>(physical, enc_W1, enc_b1, enc_ln1_g, enc_ln1_b,
                                enc_W2, enc_b2, enc_ln2_g, enc_ln2_b, h0enc);
  k_l0<<<64, 512, 0, stream>>>(W0p, bias0, wv0, xs, h0enc, o0pack);
  k_zgemm<<<4096, 256, 0, stream>>>(W1ip, o0pack, z1p);
  k_l1<<<64, 512, 0, stream>>>(W1hp, bias1, z1p, h0enc, h1b);
  k_head<<<1024, 256, 0, stream>>>(h1b, ln_g, ln_b, projWp, proj_b,
                                   hW1p, head_b1, head_W2, head_b2, qout);
  k_blend<<<1, 512, 0, stream>>>(qout, (float*)d_out);
}

// Round 4
// 376.737 us; speedup vs baseline: 6.2742x; 1.1370x over previous
//
#include <hip/hip_runtime.h>
#include <hip/hip_bf16.h>

#define BB 512
#define TT 128

typedef unsigned short u16;
typedef short v8s __attribute__((ext_vector_type(8)));
typedef float f32x4 __attribute__((ext_vector_type(4)));

#define L2E  1.4426950408889634f
#define L2E2 2.8853900817779268f

__device__ __forceinline__ u16 f2bf(float x){
  union { float f; unsigned int u; } v; v.f = x;
  unsigned int r = (v.u + 0x7fffu + ((v.u >> 16) & 1u)) >> 16;
  return (u16)r;
}
__device__ __forceinline__ float bf2f(u16 u){
  union { unsigned int i; float f; } v; v.i = ((unsigned int)u) << 16; return v.f;
}
__device__ __forceinline__ float lo_bits(unsigned u){
  union { unsigned int i; float f; } v; v.i = u << 16; return v.f;
}
__device__ __forceinline__ float hi_bits(unsigned u){
  union { unsigned int i; float f; } v; v.i = u & 0xffff0000u; return v.f;
}
// fast bf16 pack: RNE, matches f2bf
__device__ __forceinline__ uint2 pack4(f32x4 a){
  uint2 r;
  asm("v_cvt_pk_bf16_f32 %0, %1, %2" : "=v"(r.x) : "v"(a[0]), "v"(a[1]));
  asm("v_cvt_pk_bf16_f32 %0, %1, %2" : "=v"(r.y) : "v"(a[2]), "v"(a[3]));
  return r;
}
__device__ __forceinline__ float rcp_f(float x){ return __builtin_amdgcn_rcpf(x); }
#if defined(__has_builtin)
#if __has_builtin(__builtin_amdgcn_exp2f)
#define EXP2(x) __builtin_amdgcn_exp2f(x)
#endif
#endif
#ifndef EXP2
__device__ __forceinline__ float __exp2_asm(float x){
  float r; asm("v_exp_f32 %0, %1" : "=v"(r) : "v"(x)); return r;
}
#define EXP2(x) __exp2_asm(x)
#endif
// inputs prescaled by log2e (i,f,o) and 2*log2e (g)
__device__ __forceinline__ float sigm2(float y){ return rcp_f(1.f + EXP2(-y)); }   // sigmoid
__device__ __forceinline__ float tanh2(float y){ return fmaf(2.f, sigm2(y), -1.f); } // tanh (y = 2*log2e*x)

// encoder-only (unscaled) helpers
__device__ __forceinline__ float tanh_f(float x){
  float e = __expf(-2.f * fabsf(x));
  float r = (1.f - e) * rcp_f(1.f + e);
  return copysignf(r, x);
}
// barrier that waits only LDS ops: global stores/loads stay in flight
__device__ __forceinline__ void bar_lds(){
  __builtin_amdgcn_sched_barrier(0);
  asm volatile("s_waitcnt lgkmcnt(0)" ::: "memory");
  __builtin_amdgcn_s_barrier();
  __builtin_amdgcn_sched_barrier(0);
}

// ---------------- prep: pack weights (prescaled by log2e) into MFMA frag order ----
// frag layout (A and B identical): tile=j>>4, kf=k>>5,
//   lane=(j&15)+16*((k&31)>>3), elem=k&7.
__global__ __launch_bounds__(256) void k_prep(
    const float* tseq, const float* init_in,
    const float* Wih0, const float* Whh0, const float* bih0, const float* bhh0,
    const float* Wih1, const float* Whh1, const float* bih1, const float* bhh1,
    const float* projW, const float* hW1,
    float* xs, u16* W0p, u16* W1ip, u16* W1hp, u16* projWp, u16* hW1p,
    float* bias0, float* bias1, float* wv0)
{
  int tid = blockIdx.x * blockDim.x + threadIdx.x;
  int stride = gridDim.x * blockDim.x;
  for (int i = tid; i < TT*BB; i += stride){
    int t = i / BB, b = i % BB;
    xs[i] = (t == 0) ? init_in[0] : tseq[b*TT + (t-1)];
  }
  for (int i = tid; i < 2*512*128; i += stride){
    int d = i / (512*128), r = i % (512*128);
    int j = r / 128, k = r % 128;
    float sc = ((j >> 7) == 2) ? L2E2 : L2E;
    int dst = ((((d*32 + (j>>4))*4 + (k>>5))*64) + ((j&15) + 16*((k&31)>>3)))*8 + (k&7);
    W0p[dst]  = f2bf(Whh0[i] * sc);
    W1hp[dst] = f2bf(Whh1[i] * sc);
  }
  for (int i = tid; i < 2*512*256; i += stride){
    int d = i / (512*256), r = i % (512*256);
    int j = r / 256, k = r % 256;
    float sc = ((j >> 7) == 2) ? L2E2 : L2E;
    int dst = ((((d*32 + (j>>4))*8 + (k>>5))*64) + ((j&15) + 16*((k&31)>>3)))*8 + (k&7);
    W1ip[dst] = f2bf(Wih1[i] * sc);
  }
  for (int i = tid; i < 128*256; i += stride){
    int j = i / 256, k = i % 256;
    int dst = ((((j>>4)*8 + (k>>5))*64) + ((j&15) + 16*((k&31)>>3)))*8 + (k&7);
    projWp[dst] = f2bf(projW[i]);
  }
  for (int i = tid; i < 128*128; i += stride){
    int j = i / 128, k = i % 128;
    int dst = ((((j>>4)*4 + (k>>5))*64) + ((j&15) + 16*((k&31)>>3)))*8 + (k&7);
    hW1p[dst] = f2bf(hW1[i]);
  }
  for (int i = tid; i < 2*512; i += stride){
    float sc = (((i & 511) >> 7) == 2) ? L2E2 : L2E;
    bias0[i] = (bih0[i] + bhh0[i]) * sc;
    bias1[i] = (bih1[i] + bhh1[i]) * sc;
    wv0[i]   = Wih0[i] * sc;
  }
}

// ---------------- encoder ---------------------------------------------------------
__global__ __launch_bounds__(256) void k_enc(
    const float* phys, const float* W1, const float* b1, const float* g1, const float* be1,
    const float* W2, const float* b2, const float* g2, const float* be2, float* h0enc)
{
  __shared__ float eL[8][256];
  int tid = threadIdx.x;
  int rr = tid >> 5, sub = tid & 31;
  int r = blockIdx.x * 8 + rr;
  float x[16];
#pragma unroll
  for (int k = 0; k < 16; ++k) x[k] = phys[r*16 + k];
  float y[8];
#pragma unroll
  for (int jj = 0; jj < 8; ++jj){
    int j = sub*8 + jj;
    float s = b1[j];
#pragma unroll
    for (int k = 0; k < 16; ++k) s += x[k] * W1[j*16 + k];
    y[jj] = s;
  }
  float sum = 0.f, sq = 0.f;
#pragma unroll
  for (int jj = 0; jj < 8; ++jj){ sum += y[jj]; sq += y[jj]*y[jj]; }
#pragma unroll
  for (int m = 16; m >= 1; m >>= 1){ sum += __shfl_xor(sum, m, 32); sq += __shfl_xor(sq, m, 32); }
  float mu = sum / 256.f;
  float rs = rsqrtf(sq / 256.f - mu*mu + 1e-5f);
#pragma unroll
  for (int jj = 0; jj < 8; ++jj){
    int j = sub*8 + jj;
    eL[rr][j] = fmaxf((y[jj] - mu) * rs * g1[j] + be1[j], 0.f);
  }
  __syncthreads();
  float y2[4];
#pragma unroll
  for (int jj = 0; jj < 4; ++jj){
    int j2 = sub*4 + jj;
    float s = b2[j2];
    const float* wrow = W2 + j2*256;
    for (int k = 0; k < 256; k += 4)
      s += eL[rr][k]*wrow[k] + eL[rr][k+1]*wrow[k+1] + eL[rr][k+2]*wrow[k+2] + eL[rr][k+3]*wrow[k+3];
    y2[jj] = s;
  }
  sum = 0.f; sq = 0.f;
#pragma unroll
  for (int jj = 0; jj < 4; ++jj){ sum += y2[jj]; sq += y2[jj]*y2[jj]; }
#pragma unroll
  for (int m = 16; m >= 1; m >>= 1){ sum += __shfl_xor(sum, m, 32); sq += __shfl_xor(sq, m, 32); }
  mu = sum / 128.f;
  rs = rsqrtf(sq / 128.f - mu*mu + 1e-5f);
#pragma unroll
  for (int jj = 0; jj < 4; ++jj){
    int j2 = sub*4 + jj;
    h0enc[r*128 + j2] = tanh_f((y2[jj]-mu)*rs*g2[j2] + be2[j2]);
  }
}

// ---------------- layer0 recurrence: weights truly in VGPRs (256-reg cap) ---------
__global__ __launch_bounds__(512) void k_l0(
    const u16* W0p, const float* bias0, const float* wv0, const float* xs,
    const float* h0enc, u16* o0pack)
{
  __shared__ __align__(16) u16 Xb[2][4][512];
  __shared__ __align__(16) float xl[TT*16];
  int bx = blockIdx.x;
  int tile = bx & 31, d = bx >> 5;
  int tid = threadIdx.x, w = tid >> 6, l = tid & 63;
  int r0 = tile * 16, lrow = l & 15, lk = l >> 4;

  for (int i = tid; i < TT*16; i += 512){
    int t = i >> 4, r = i & 15;
    xl[i] = xs[t*BB + r0 + r];
  }
  if (tid < 256){
    int kf = tid >> 6, ll = tid & 63;
    const float* src = h0enc + (r0 + (ll & 15))*128 + kf*32 + 8*(ll >> 4);
    u16* dstp = &Xb[0][kf][ll*8];
#pragma unroll
    for (int i = 0; i < 8; ++i) dstp[i] = f2bf(src[i]);
  }

  const u16* Wb = W0p + (size_t)d*32*4*512;
  v8s wa[4][4];
#pragma unroll
  for (int q = 0; q < 4; ++q)
#pragma unroll
    for (int kf = 0; kf < 4; ++kf)
      wa[q][kf] = *(const v8s*)(Wb + (size_t)(((w + 8*q)*4 + kf)*64 + l)*8);

  float bias[4][4], wv[4][4];
#pragma unroll
  for (int q = 0; q < 4; ++q){
    int tq = w + 8*q;
#pragma unroll
    for (int jj = 0; jj < 4; ++jj){
      int j = tq*16 + 4*lk + jj;
      bias[q][jj] = bias0[d*512 + j];
      wv[q][jj]   = wv0[d*512 + j];
    }
  }
  float c[4] = {0.f,0.f,0.f,0.f};
  int jout = w*16 + 4*lk;
  int kfx = jout >> 5;
  int sl  = lrow + 16*((jout & 31) >> 3);
  int eb  = jout & 7;
  int kfo = 4*d + kfx;
  __syncthreads();

#pragma unroll 2
  for (int t = 0; t < TT; ++t){
    int cur = t & 1, nxt = cur ^ 1;
    v8s bfr[4];
#pragma unroll
    for (int kf = 0; kf < 4; ++kf) bfr[kf] = *(const v8s*)&Xb[cur][kf][l*8];
    float xv = xl[t*16 + lrow];
    f32x4 acc[4];
#pragma unroll
    for (int q = 0; q < 4; ++q)
#pragma unroll
      for (int jj = 0; jj < 4; ++jj)
        acc[q][jj] = fmaf(xv, wv[q][jj], bias[q][jj]);
#pragma unroll
    for (int kf = 0; kf < 4; ++kf)
#pragma unroll
      for (int q = 0; q < 4; ++q)
        acc[q] = __builtin_amdgcn_mfma_f32_16x16x32_bf16(wa[q][kf], bfr[kf], acc[q], 0, 0, 0);
    f32x4 hv;
#pragma unroll
    for (int jj = 0; jj < 4; ++jj){
      float si = sigm2(acc[0][jj]);
      float sf = sigm2(acc[1][jj]);
      float tg = tanh2(acc[2][jj]);
      float so = sigm2(acc[3][jj]);
      float cn = fmaf(sf, c[jj], si*tg);
      c[jj] = cn;
      float s2 = sigm2(L2E2 * cn);
      hv[jj] = so * fmaf(2.f, s2, -1.f);
    }
    uint2 hp = pack4(hv);
    *(uint2*)&Xb[nxt][kfx][sl*8 + eb] = hp;
    size_t off = ((((size_t)t*32 + tile)*8 + kfo)*64 + sl)*8 + eb;
    *(uint2*)&o0pack[off] = hp;     // fire-and-forget
    bar_lds();
  }
}

// ---------------- Z1 = bias1 + o0 @ Wih1^T (parallel GEMM, bf16 out) --------------
__global__ __launch_bounds__(256) void k_zgemm(
    const u16* W1ip, const float* bias1p, const u16* o0pack, u16* z1p)
{
  int bx = blockIdx.x;
  int nc = bx & 3, bg = (bx >> 2) & 7, t = bx >> 5;
  int w = threadIdx.x >> 6, l = threadIdx.x & 63;
  int btile = bg*4 + w;
  int lk4 = (l >> 4) * 4;
  v8s bfrag[8];
#pragma unroll
  for (int kf = 0; kf < 8; ++kf)
    bfrag[kf] = *(const v8s*)&o0pack[((((size_t)t*32 + btile)*8 + kf)*64 + l)*8];
  f32x4 acc[16];
#pragma unroll
  for (int nt = 0; nt < 16; ++nt){
    int ntg = nc*16 + nt;
    acc[nt] = *(const f32x4*)&bias1p[(ntg >> 5)*512 + (ntg & 31)*16 + lk4];
  }
#pragma unroll
  for (int kf = 0; kf < 8; ++kf){
#pragma unroll
    for (int nt = 0; nt < 16; ++nt){
      int ntg = nc*16 + nt;
      int dir = ntg >> 5, tl = ntg & 31;
      v8s a = *(const v8s*)&W1ip[((((size_t)dir*32 + tl)*8 + kf)*64 + l)*8];
      acc[nt] = __builtin_amdgcn_mfma_f32_16x16x32_bf16(a, bfrag[kf], acc[nt], 0, 0, 0);
    }
  }
#pragma unroll
  for (int nt = 0; nt < 16; ++nt){
    int ntg = nc*16 + nt;
    uint2 zp = pack4(acc[nt]);
    *(uint2*)&z1p[((((size_t)t*32 + btile)*64 + ntg)*64 + l)*4] = zp;
  }
}

// ---------------- layer1 recurrence: Whh in VGPRs, depth-2 Z prefetch -------------
__global__ __launch_bounds__(512) void k_l1(
    const u16* W1hp, const u16* z1p, const float* h0enc, u16* h1b)
{
  __shared__ __align__(16) u16 Xh[2][4][512];
  int bx = blockIdx.x;
  int tile = bx & 31, d = bx >> 5;
  int tid = threadIdx.x, w = tid >> 6, l = tid & 63;
  int r0 = tile * 16, lrow = l & 15, lk = l >> 4;

  if (tid < 256){
    int kf = tid >> 6, ll = tid & 63;
    const float* src = h0enc + (r0 + (ll & 15))*128 + kf*32 + 8*(ll >> 4);
    u16* dstp = &Xh[0][kf][ll*8];
#pragma unroll
    for (int i = 0; i < 8; ++i) dstp[i] = f2bf(src[i]);
  }

  const u16* Wh = W1hp + (size_t)d*32*4*512;
  v8s wh[4][4];
#pragma unroll
  for (int q = 0; q < 4; ++q)
#pragma unroll
    for (int kf = 0; kf < 4; ++kf)
      wh[q][kf] = *(const v8s*)(Wh + (size_t)(((w + 8*q)*4 + kf)*64 + l)*8);

  float c[4] = {0.f,0.f,0.f,0.f};
  int jout = w*16 + 4*lk;
  int kfx = jout >> 5;
  int sl  = lrow + 16*((jout & 31) >> 3);
  int eb  = jout & 7;
  int zcol = d*32 + w;    // base ntg for q=0

  uint2 zr[4], zn[4];
#pragma unroll
  for (int q = 0; q < 4; ++q)
    zr[q] = *(const uint2*)&z1p[(((size_t)tile*64 + zcol + 8*q)*64 + l)*4];
#pragma unroll
  for (int q = 0; q < 4; ++q)
    zn[q] = *(const uint2*)&z1p[((((size_t)1*32 + tile)*64 + zcol + 8*q)*64 + l)*4];
  __syncthreads();

#pragma unroll 2
  for (int t = 0; t < TT; ++t){
    int cur = t & 1, nxt = cur ^ 1;
    v8s bh[4];
#pragma unroll
    for (int kf = 0; kf < 4; ++kf) bh[kf] = *(const v8s*)&Xh[cur][kf][l*8];
    f32x4 acc[4];
#pragma unroll
    for (int q = 0; q < 4; ++q){
      acc[q][0] = lo_bits(zr[q].x);
      acc[q][1] = hi_bits(zr[q].x);
      acc[q][2] = lo_bits(zr[q].y);
      acc[q][3] = hi_bits(zr[q].y);
    }
#pragma unroll
    for (int kf = 0; kf < 4; ++kf)
#pragma unroll
      for (int q = 0; q < 4; ++q)
        acc[q] = __builtin_amdgcn_mfma_f32_16x16x32_bf16(wh[q][kf], bh[kf], acc[q], 0, 0, 0);
    f32x4 hv;
#pragma unroll
    for (int jj = 0; jj < 4; ++jj){
      float si = sigm2(acc[0][jj]);
      float sf = sigm2(acc[1][jj]);
      float tg = tanh2(acc[2][jj]);
      float so = sigm2(acc[3][jj]);
      float cn = fmaf(sf, c[jj], si*tg);
      c[jj] = cn;
      float s2 = sigm2(L2E2 * cn);
      hv[jj] = so * fmaf(2.f, s2, -1.f);
    }
    uint2 hp = pack4(hv);
    *(uint2*)&Xh[nxt][kfx][sl*8 + eb] = hp;
    int hidx = ((t*BB + r0 + lrow) << 8) + (d << 7) + jout;
    *(uint2*)&h1b[hidx] = hp;       // fire-and-forget
    // rotate prefetch regs (zn loaded ~1 iter ago) and issue t+2
#pragma unroll
    for (int q = 0; q < 4; ++q) zr[q] = zn[q];
    int tp = (t + 2 < TT) ? t + 2 : TT - 1;
#pragma unroll
    for (int q = 0; q < 4; ++q)
      zn[q] = *(const uint2*)&z1p[((((size_t)tp*32 + tile)*64 + zcol + 8*q)*64 + l)*4];
    bar_lds();
  }
}

// ---------------- head: LN -> proj -> relu head1 -> head2 via MFMA ---------------
__global__ __launch_bounds__(256) void k_head(
    const u16* h1b, const float* lng, const float* lnb,
    const u16* projWp, const float* projb,
    const u16* hW1p, const float* hb1, const float* hW2, const float* hb2,
    float* qout)
{
  __shared__ __align__(16) u16 xls[4][16*256];  // 32 KB, swizzled
  __shared__ __align__(16) u16 pls[4][16*128];  // 16 KB, swizzled
  int w = threadIdx.x >> 6, l = threadIdx.x & 63;
  size_t g0 = (size_t)blockIdx.x*64 + w*16;
  int row = l >> 2, qc = l & 3;

  const u16* srcb = h1b + (g0 + row)*256;
  f32x4 v[16];
#pragma unroll
  for (int m = 0; m < 16; ++m){
    uint2 p = *(const uint2*)&srcb[m*16 + qc*4];
    v[m][0] = lo_bits(p.x);
    v[m][1] = hi_bits(p.x);
    v[m][2] = lo_bits(p.y);
    v[m][3] = hi_bits(p.y);
  }
  float sum = 0.f, sq = 0.f;
#pragma unroll
  for (int m = 0; m < 16; ++m){
#pragma unroll
    for (int i = 0; i < 4; ++i){ sum += v[m][i]; sq += v[m][i]*v[m][i]; }
  }
  sum += __shfl_xor(sum, 1); sq += __shfl_xor(sq, 1);
  sum += __shfl_xor(sum, 2); sq += __shfl_xor(sq, 2);
  float mu = sum / 256.f;
  float rs = rsqrtf(sq / 256.f - mu*mu + 1e-5f);
  u16* xw = xls[w];
  int rsw = (row & 7) << 3;    // 16B-granule XOR swizzle, u16 units
#pragma unroll
  for (int m = 0; m < 16; ++m){
    int cb = m*16 + qc*4;
    f32x4 gq = *(const f32x4*)&lng[cb];
    f32x4 bq = *(const f32x4*)&lnb[cb];
    f32x4 xn;
#pragma unroll
    for (int i = 0; i < 4; ++i) xn[i] = (v[m][i]-mu)*rs*gq[i] + bq[i];
    *(uint2*)&xw[(row*256 + cb) ^ rsw] = pack4(xn);
  }

  // proj: (16x256)@(256x128) MFMA
  int lk = l >> 4, r = l & 15;
  int rsw2 = (r & 7) << 3;
  f32x4 acc[8];
#pragma unroll
  for (int nt = 0; nt < 8; ++nt) acc[nt] = *(const f32x4*)&projb[nt*16 + lk*4];
#pragma unroll
  for (int kf = 0; kf < 8; ++kf){
    v8s b = *(const v8s*)&xw[(r*256 + kf*32 + lk*8) ^ rsw2];
#pragma unroll
    for (int nt = 0; nt < 8; ++nt){
      v8s a = *(const v8s*)&projWp[(((size_t)nt*8 + kf)*64 + l)*8];
      acc[nt] = __builtin_amdgcn_mfma_f32_16x16x32_bf16(a, b, acc[nt], 0, 0, 0);
    }
  }
  u16* pw = pls[w];
#pragma unroll
  for (int nt = 0; nt < 8; ++nt)
    *(uint2*)&pw[(r*128 + nt*16 + lk*4) ^ rsw2] = pack4(acc[nt]);

  // head1: (16x128)@(128x128) MFMA
  f32x4 acc2[8];
#pragma unroll
  for (int nt = 0; nt < 8; ++nt) acc2[nt] = *(const f32x4*)&hb1[nt*16 + lk*4];
#pragma unroll
  for (int kf = 0; kf < 4; ++kf){
    v8s b = *(const v8s*)&pw[(r*128 + kf*32 + lk*8) ^ rsw2];
#pragma unroll
    for (int nt = 0; nt < 8; ++nt){
      v8s a = *(const v8s*)&hW1p[(((size_t)nt*4 + kf)*64 + l)*8];
      acc2[nt] = __builtin_amdgcn_mfma_f32_16x16x32_bf16(a, b, acc2[nt], 0, 0, 0);
    }
  }
  // head2: relu + dot with hW2, reduce lanes sharing r
  float part = 0.f;
#pragma unroll
  for (int nt = 0; nt < 8; ++nt){
    f32x4 w2 = *(const f32x4*)&hW2[nt*16 + lk*4];
#pragma unroll
    for (int jj = 0; jj < 4; ++jj) part += fmaxf(acc2[nt][jj], 0.f) * w2[jj];
  }
  part += __shfl_xor(part, 16);
  part += __shfl_xor(part, 32);
  if (l < 16) qout[g0 + l] = part + hb2[0];
}

// ---------------- AR blend --------------------------------------------------------
__global__ __launch_bounds__(512) void k_blend(const float* qout, float* out)
{
  int b = threadIdx.x;
  float pred = 0.f;
  for (int t0 = 0; t0 < TT; t0 += 16){
    float v[16];
#pragma unroll
    for (int i = 0; i < 16; ++i) v[i] = qout[(t0+i)*BB + b];
#pragma unroll
    for (int i = 0; i < 16; ++i){
      pred = (t0 + i == 0) ? v[i] : 0.8f*v[i] + 0.2f*pred;
      out[b*TT + t0 + i] = pred;
    }
  }
}

extern "C" void kernel_launch(void* const* d_in, const int* in_sizes, int n_in,
                              void* d_out, int out_size, void* d_ws, size_t ws_size,
                              hipStream_t stream) {
  const float* physical   = (const float*)d_in[0];
  const float* target_seq = (const float*)d_in[1];
  const float* enc_W1     = (const float*)d_in[2];
  const float* enc_b1     = (const float*)d_in[3];
  const float* enc_ln1_g  = (const float*)d_in[4];
  const float* enc_ln1_b  = (const float*)d_in[5];
  const float* enc_W2     = (const float*)d_in[6];
  const float* enc_b2     = (const float*)d_in[7];
  const float* enc_ln2_g  = (const float*)d_in[8];
  const float* enc_ln2_b  = (const float*)d_in[9];
  const float* Wih0       = (const float*)d_in[10];
  const float* Whh0       = (const float*)d_in[11];
  const float* bih0       = (const float*)d_in[12];
  const float* bhh0       = (const float*)d_in[13];
  const float* Wih1       = (const float*)d_in[14];
  const float* Whh1       = (const float*)d_in[15];
  const float* bih1       = (const float*)d_in[16];
  const float* bhh1       = (const float*)d_in[17];
  const float* ln_g       = (const float*)d_in[18];
  const float* ln_b       = (const float*)d_in[19];
  const float* proj_W     = (const float*)d_in[20];
  const float* proj_b     = (const float*)d_in[21];
  const float* head_W1    = (const float*)d_in[22];
  const float* head_b1    = (const float*)d_in[23];
  const float* head_W2    = (const float*)d_in[24];
  const float* head_b2    = (const float*)d_in[25];
  const float* init_input = (const float*)d_in[26];

  size_t off = 0;
  char* base = (char*)d_ws;
  auto carve = [&](size_t bytes) -> void* {
    void* p = base + off;
    off += (bytes + 255) & ~(size_t)255;
    return p;
  };
  u16*   o0pack  = (u16*)  carve((size_t)TT*32*8*64*8*2);     // 32 MB bf16 frag-packed
  u16*   h1b     = (u16*)  carve((size_t)TT*BB*256*2);        // 32 MB bf16
  u16*   z1p     = (u16*)  carve((size_t)TT*32*64*64*4*2);    // 128 MB bf16 C-frag
  float* qout    = (float*)carve((size_t)TT*BB*4);
  float* h0enc   = (float*)carve((size_t)BB*128*4);
  float* xs      = (float*)carve((size_t)TT*BB*4);
  u16*   W0p     = (u16*)  carve((size_t)2*512*128*2);
  u16*   W1ip    = (u16*)  carve((size_t)2*512*256*2);
  u16*   W1hp    = (u16*)  carve((size_t)2*512*128*2);
  u16*   projWp  = (u16*)  carve((size_t)128*256*2);
  u16*   hW1p    = (u16*)  carve((size_t)128*128*2);
  float* bias0   = (float*)carve(4096);
  float* bias1   = (float*)carve(4096);
  float* wv0     = (float*)carve(4096);

  k_prep<<<256, 256, 0, stream>>>(target_seq, init_input, Wih0, Whh0, bih0, bhh0,
                                  Wih1, Whh1, bih1, bhh1, proj_W, head_W1,
                                  xs, W0p, W1ip, W1hp, projWp, hW1p,
                                  bias0, bias1, wv0);
  k_enc<<<64, 256, 0, stream>>>(physical, enc_W1, enc_b1, enc_ln1_g, enc_ln1_b,
                                enc_W2, enc_b2, enc_ln2_g, enc_ln2_b, h0enc);
  k_l0<<<64, 512, 0, stream>>>(W0p, bias0, wv0, xs, h0enc, o0pack);
  k_zgemm<<<4096, 256, 0, stream>>>(W1ip, bias1, o0pack, z1p);
  k_l1<<<64, 512, 0, stream>>>(W1hp, z1p, h0enc, h1b);
  k_head<<<1024, 256, 0, stream>>>(h1b, ln_g, ln_b, projWp, proj_b,
                                   hW1p, head_b1, head_W2, head_b2, qout);
  k_blend<<<1, 512, 0, stream>>>(qout, (float*)d_out);
}